// Round 5
// baseline (9207.977 us; speedup 1.0000x reference)
//
#include <hip/hip_runtime.h>
#include <stdint.h>

typedef unsigned short u16;
typedef unsigned int   u32;
typedef __attribute__((ext_vector_type(8))) short bf8v;          // 8 x bf16 MFMA frag (4 VGPR)
typedef __attribute__((ext_vector_type(4))) float f4v;           // MFMA acc frag
typedef __attribute__((ext_vector_type(8))) unsigned short us8v; // 16B bf16 vector

#define LSTR 40   // padded LDS row stride (u16) for 32-elem bf16 rows

__device__ __forceinline__ float bfs(u16 u){ union { u32 i; float f; } v; v.i = ((u32)u) << 16; return v.f; }
__device__ __forceinline__ u16 f2bf(float f){ union { float f; u32 i; } v; v.f = f; u32 i = v.i; return (u16)((i + 0x7fffu + ((i >> 16) & 1u)) >> 16); }
__device__ __forceinline__ float sigm(float x){ return 1.f / (1.f + __expf(-x)); }
__device__ __forceinline__ float tanh_(float x){ float e = __expf(2.f * x); return 1.f - 2.f / (e + 1.f); }

// ---- device-scope grid barrier: pollers use coherent LOADS (no RMW contention) ----
__device__ __forceinline__ void gbar(int* bar){
  __syncthreads();                       // all block's prior mem ops drained
  if (threadIdx.x == 0){
    __threadfence();                     // release: block's writes visible device-wide
    int g = __hip_atomic_load(&bar[1], __ATOMIC_RELAXED, __HIP_MEMORY_SCOPE_AGENT);
    int arrived = __hip_atomic_fetch_add(&bar[0], 1, __ATOMIC_RELAXED, __HIP_MEMORY_SCOPE_AGENT);
    if (arrived == (int)gridDim.x - 1){
      __hip_atomic_store(&bar[0], 0, __ATOMIC_RELAXED, __HIP_MEMORY_SCOPE_AGENT);
      __hip_atomic_store(&bar[1], g + 1, __ATOMIC_RELEASE, __HIP_MEMORY_SCOPE_AGENT);
    } else {
      while (__hip_atomic_load(&bar[1], __ATOMIC_RELAXED, __HIP_MEMORY_SCOPE_AGENT) == g)
        __builtin_amdgcn_s_sleep(4);
    }
    __threadfence();                     // acquire: discard stale cached lines
  }
  __syncthreads();
}

// ---------------- one-time / chunked prep ----------------

__global__ __launch_bounds__(256) void k_transpose_fm(const float* __restrict__ fm, u16* __restrict__ out, int b_base){
  __shared__ u16 tile[64][65];
  int b = blockIdx.z, hw0 = blockIdx.x * 64, ci0 = blockIdx.y * 64;
  int tid = threadIdx.x;
  int hwl = tid & 63, ci_l = tid >> 6;
  #pragma unroll
  for (int r = 0; r < 16; ++r){
    int ci = ci_l * 16 + r;
    tile[ci][hwl] = f2bf(fm[((size_t)((b_base + b) * 512 + ci0 + ci)) * 256 + hw0 + hwl]);
  }
  __syncthreads();
  int cil = tid & 63, hw_l = tid >> 6;
  #pragma unroll
  for (int r = 0; r < 16; ++r){
    int hw = hw_l * 16 + r;
    out[((size_t)(b * 256 + hw0 + hw)) * 512 + ci0 + cil] = tile[cil][hw];
  }
}

__global__ __launch_bounds__(256) void k_wt_prep(const float* __restrict__ w, u16* __restrict__ wt){
  int idx = blockIdx.x * 256 + threadIdx.x;         // 9*512*512
  int ci = idx & 511, co = (idx >> 9) & 511, dydx = idx >> 18;
  wt[idx] = f2bf(w[((size_t)(co * 512 + ci)) * 9 + dydx]);
}

__global__ __launch_bounds__(256) void k_cvt(const float* __restrict__ src, u16* __restrict__ dst, int n){
  int idx = blockIdx.x * 256 + threadIdx.x;
  if (idx < n) dst[idx] = f2bf(src[idx]);
}
__global__ __launch_bounds__(256) void k_cvt_rw1(const float* __restrict__ src, u16* __restrict__ dst){
  int idx = blockIdx.x * 256 + threadIdx.x;   // 2048*512
  int n = idx >> 9, k = idx & 511;
  dst[idx] = f2bf(src[(size_t)n * 550 + k]);
}
__global__ __launch_bounds__(256) void k_cvt_gen(const float* __restrict__ src, u16* __restrict__ dst){
  int idx = blockIdx.x * 256 + threadIdx.x;   // 48*512
  int n = idx >> 9, k = idx & 511;
  dst[idx] = (n < 38) ? f2bf(src[(size_t)n * 512 + k]) : (u16)0;
}
__global__ __launch_bounds__(256) void k_cvt_t(const float* __restrict__ src, u16* __restrict__ dst){
  __shared__ float tile[32][33];
  int c0 = blockIdx.x * 32, r0 = blockIdx.y * 32;
  int tx = threadIdx.x & 31, ty = threadIdx.x >> 5;
  #pragma unroll
  for (int rr = ty; rr < 32; rr += 8)
    tile[rr][tx] = src[(size_t)(r0 + rr) * 512 + c0 + tx];
  __syncthreads();
  #pragma unroll
  for (int rr = ty; rr < 32; rr += 8)
    dst[(size_t)(c0 + rr) * 512 + r0 + tx] = f2bf(tile[tx][rr]);
}
__global__ __launch_bounds__(256) void k_bfold(const float* __restrict__ W, const float* __restrict__ vin,
    const float* __restrict__ a1, const float* __restrict__ a2, float* __restrict__ out, int N){
  int n = blockIdx.x * 256 + threadIdx.x;
  if (n >= N) return;
  float s = a1 ? a1[n] : 0.f;
  if (a2) s += a2[n];
  const float* wr = W + (size_t)n * 512;
  float acc0 = 0.f, acc1 = 0.f, acc2 = 0.f, acc3 = 0.f;
  for (int k = 0; k < 512; k += 4){
    acc0 = fmaf(wr[k],   vin[k],   acc0);
    acc1 = fmaf(wr[k+1], vin[k+1], acc1);
    acc2 = fmaf(wr[k+2], vin[k+2], acc2);
    acc3 = fmaf(wr[k+3], vin[k+3], acc3);
  }
  out[n] = s + ((acc0 + acc1) + (acc2 + acc3));
}
__global__ __launch_bounds__(256) void k_addrow(float* __restrict__ dst, const float* __restrict__ row){
  int idx = blockIdx.x * 256 + threadIdx.x;  // 131072
  dst[idx] += row[idx & 511];
}

// ---------------- conv3x3 as implicit GEMM (unchanged: control) ----------------
__global__ __launch_bounds__(256) void k_conv(
    const u16* __restrict__ in_t, const u16* __restrict__ Wt,
    const float* __restrict__ cbias, u16* __restrict__ fmh, int b_base)
{
  __shared__ u16 As[128 * LSTR];
  __shared__ u16 Bs[128 * LSTR];
  int tid = threadIdx.x;
  int wave = tid >> 6, lane = tid & 63;
  int nb = blockIdx.x & 3, mb = blockIdx.x >> 2;
  int m0 = mb * 128, n0 = nb * 128;
  int bb = m0 >> 8;
  int r = tid >> 1;
  int seg = (tid & 1) * 16;
  int hwl = (mb & 1) * 128 + r;
  int y = hwl >> 5, x = hwl & 31;
  const u16* aBase = in_t + ((size_t)bb * 256) * 512 + seg;
  const u16* bBase = Wt + ((size_t)(n0 + r)) * 512 + seg;
  int lm = lane & 15, quad = lane >> 4;
  int wm = (wave & 1) * 64, wn = (wave >> 1) * 64;
  f4v acc[4][4];
  #pragma unroll
  for (int i = 0; i < 4; ++i)
    #pragma unroll
    for (int j = 0; j < 4; ++j)
      acc[i][j] = (f4v){0.f, 0.f, 0.f, 0.f};

  us8v pa0, pa1, pb0, pb1;
  auto LDC = [&](int i){
    int dydx = i >> 4, kc = i & 15;
    int dy = dydx / 3, dx = dydx - dy * 3;
    int yy = y + dy - 1, xx = x + dx - 1;
    bool ok = (yy >= 0) && (yy < 8) && (xx >= 0) && (xx < 32);
    const u16* aRow = aBase + (ptrdiff_t)(yy * 32 + xx) * 512 + kc * 32;
    const u16* bRow = bBase + (size_t)dydx * 262144 + kc * 32;
    if (ok){ pa0 = *(const us8v*)aRow; pa1 = *(const us8v*)(aRow + 8); }
    else   { pa0 = (us8v){0,0,0,0,0,0,0,0}; pa1 = pa0; }
    pb0 = *(const us8v*)bRow; pb1 = *(const us8v*)(bRow + 8);
  };
  LDC(0);
  for (int i = 0; i < 144; ++i){
    __syncthreads();
    *(us8v*)&As[r * LSTR + seg]     = pa0;
    *(us8v*)&As[r * LSTR + seg + 8] = pa1;
    *(us8v*)&Bs[r * LSTR + seg]     = pb0;
    *(us8v*)&Bs[r * LSTR + seg + 8] = pb1;
    __syncthreads();
    if (i < 143) LDC(i + 1);
    bf8v af[4], bfr[4];
    #pragma unroll
    for (int ii = 0; ii < 4; ++ii) af[ii]  = *(const bf8v*)&As[(wm + ii * 16 + lm) * LSTR + quad * 8];
    #pragma unroll
    for (int jj = 0; jj < 4; ++jj) bfr[jj] = *(const bf8v*)&Bs[(wn + jj * 16 + lm) * LSTR + quad * 8];
    #pragma unroll
    for (int ii = 0; ii < 4; ++ii)
      #pragma unroll
      for (int jj = 0; jj < 4; ++jj)
        acc[ii][jj] = __builtin_amdgcn_mfma_f32_16x16x32_bf16(af[ii], bfr[jj], acc[ii][jj], 0, 0, 0);
  }
  #pragma unroll
  for (int j = 0; j < 4; ++j){
    int co = n0 + wn + j * 16 + lm;
    float bv = cbias[co];
    #pragma unroll
    for (int i = 0; i < 4; ++i){
      int mrow = m0 + wm + i * 16 + quad * 4;
      int hw = mrow & 255;
      ushort4 pk;
      pk.x = f2bf(acc[i][j][0] + bv);
      pk.y = f2bf(acc[i][j][1] + bv);
      pk.z = f2bf(acc[i][j][2] + bv);
      pk.w = f2bf(acc[i][j][3] + bv);
      *(ushort4*)&fmh[((size_t)((b_base + bb) * 512 + co)) * 256 + hw] = pk;
    }
  }
}

// ---------------- 128x128 GEMM tile body (precompute GEMMs) ----------------
__device__ __forceinline__ void gemm_tile(
    const u16* __restrict__ A, const u16* __restrict__ W,
    const float* __restrict__ b1, const float* __restrict__ C0,
    void* __restrict__ out, int obf16, int N, int m0, int n0,
    u16* As, u16* Bs)
{
  int tid = threadIdx.x;
  int wave = tid >> 6, lane = tid & 63;
  int r = tid >> 1, seg = (tid & 1) * 16;
  int lm = lane & 15, quad = lane >> 4;
  int wm = (wave & 1) * 64, wn = (wave >> 1) * 64;
  f4v acc[4][4];
  #pragma unroll
  for (int i = 0; i < 4; ++i)
    #pragma unroll
    for (int j = 0; j < 4; ++j)
      acc[i][j] = (f4v){0.f, 0.f, 0.f, 0.f};
  const u16* aRow = A + (size_t)(m0 + r) * 512 + seg;
  const u16* bRow = W + (size_t)(n0 + r) * 512 + seg;
  us8v pa0 = *(const us8v*)aRow, pa1 = *(const us8v*)(aRow + 8);
  us8v pb0 = *(const us8v*)bRow, pb1 = *(const us8v*)(bRow + 8);
  for (int kc = 0; kc < 16; ++kc){
    __syncthreads();
    *(us8v*)&As[r * LSTR + seg]     = pa0;
    *(us8v*)&As[r * LSTR + seg + 8] = pa1;
    *(us8v*)&Bs[r * LSTR + seg]     = pb0;
    *(us8v*)&Bs[r * LSTR + seg + 8] = pb1;
    __syncthreads();
    if (kc < 15){
      pa0 = *(const us8v*)(aRow + (kc + 1) * 32);
      pa1 = *(const us8v*)(aRow + (kc + 1) * 32 + 8);
      pb0 = *(const us8v*)(bRow + (kc + 1) * 32);
      pb1 = *(const us8v*)(bRow + (kc + 1) * 32 + 8);
    }
    bf8v af[4], bfr[4];
    #pragma unroll
    for (int i = 0; i < 4; ++i) af[i]  = *(const bf8v*)&As[(wm + i * 16 + lm) * LSTR + quad * 8];
    #pragma unroll
    for (int j = 0; j < 4; ++j) bfr[j] = *(const bf8v*)&Bs[(wn + j * 16 + lm) * LSTR + quad * 8];
    #pragma unroll
    for (int i = 0; i < 4; ++i)
      #pragma unroll
      for (int j = 0; j < 4; ++j)
        acc[i][j] = __builtin_amdgcn_mfma_f32_16x16x32_bf16(af[i], bfr[j], acc[i][j], 0, 0, 0);
  }
  #pragma unroll
  for (int j = 0; j < 4; ++j){
    int n = n0 + wn + j * 16 + lm;
    float badd = b1 ? b1[n] : 0.f;
    #pragma unroll
    for (int i = 0; i < 4; ++i){
      int mb = m0 + wm + i * 16 + quad * 4;
      #pragma unroll
      for (int reg = 0; reg < 4; ++reg){
        int m = mb + reg;
        float v = acc[i][j][reg] + badd;
        if (C0) v += C0[(size_t)m * N + n];
        if (obf16) ((u16*)out)[(size_t)m * N + n] = f2bf(v);
        else       ((float*)out)[(size_t)m * N + n] = v;
      }
    }
  }
}

__global__ __launch_bounds__(256) void k_mgemm(
    const u16* __restrict__ A, const u16* __restrict__ W,
    const float* __restrict__ b1, const float* __restrict__ C0,
    void* __restrict__ out, int obf16, int N)
{
  __shared__ u16 As[128 * LSTR];
  __shared__ u16 Bs[128 * LSTR];
  gemm_tile(A, W, b1, C0, out, obf16, N, blockIdx.y * 128, blockIdx.x * 128, As, Bs);
}

// ---------------- 64x64 GEMM tile body (persistent-kernel phases) ----------------
__device__ __forceinline__ void gemm64(
    const u16* __restrict__ A, const u16* __restrict__ W,
    const float* __restrict__ bias, const float* __restrict__ C0,
    void* __restrict__ out, int obf16, int N, int m0, int n0,
    u16* As, u16* Bs)
{
  int tid = threadIdx.x;
  int wave = tid >> 6, lane = tid & 63;
  int lm = lane & 15, quad = lane >> 4;
  int wm = (wave >> 1) * 32, wn = (wave & 1) * 32;
  int sr = tid >> 2, sseg = (tid & 3) * 8;
  f4v acc[2][2];
  #pragma unroll
  for (int i = 0; i < 2; ++i)
    #pragma unroll
    for (int j = 0; j < 2; ++j)
      acc[i][j] = (f4v){0.f, 0.f, 0.f, 0.f};
  const u16* aRow = A + (size_t)(m0 + sr) * 512 + sseg;
  const u16* bRow = W + (size_t)(n0 + sr) * 512 + sseg;
  us8v pa = *(const us8v*)aRow, pb = *(const us8v*)bRow;
  for (int kc = 0; kc < 16; ++kc){
    __syncthreads();
    *(us8v*)&As[sr * LSTR + sseg] = pa;
    *(us8v*)&Bs[sr * LSTR + sseg] = pb;
    __syncthreads();
    if (kc < 15){
      pa = *(const us8v*)(aRow + (kc + 1) * 32);
      pb = *(const us8v*)(bRow + (kc + 1) * 32);
    }
    bf8v af[2], bfr[2];
    #pragma unroll
    for (int i = 0; i < 2; ++i) af[i]  = *(const bf8v*)&As[(wm + i * 16 + lm) * LSTR + quad * 8];
    #pragma unroll
    for (int j = 0; j < 2; ++j) bfr[j] = *(const bf8v*)&Bs[(wn + j * 16 + lm) * LSTR + quad * 8];
    #pragma unroll
    for (int i = 0; i < 2; ++i)
      #pragma unroll
      for (int j = 0; j < 2; ++j)
        acc[i][j] = __builtin_amdgcn_mfma_f32_16x16x32_bf16(af[i], bfr[j], acc[i][j], 0, 0, 0);
  }
  #pragma unroll
  for (int j = 0; j < 2; ++j){
    int n = n0 + wn + j * 16 + lm;
    float badd = bias ? bias[n] : 0.f;
    #pragma unroll
    for (int i = 0; i < 2; ++i){
      #pragma unroll
      for (int reg = 0; reg < 4; ++reg){
        int m = m0 + wm + i * 16 + quad * 4 + reg;
        float v = acc[i][j][reg] + badd;
        if (C0) v += C0[(size_t)m * N + n];
        if (obf16) ((u16*)out)[(size_t)m * N + n] = f2bf(v);
        else       ((float*)out)[(size_t)m * N + n] = v;
      }
    }
  }
}

// ---------------- fused gates GEMM + LSTM body ----------------
__device__ __forceinline__ void glstm_body(u16* As, u16* Bs, int bx, int by,
    const u16* __restrict__ A1, const u16* __restrict__ W1,
    const u16* __restrict__ A2, const u16* __restrict__ W2,
    const float* __restrict__ b1, const float* __restrict__ b2,
    const float* __restrict__ C0,
    const float* __restrict__ Woh, const int* __restrict__ txt, int t,
    u16* __restrict__ hn, float* __restrict__ c_io,
    u16* __restrict__ hidout)
{
  int tid = threadIdx.x;
  int wave = tid >> 6, lane = tid & 63;
  int lm = lane & 15, quad = lane >> 4;
  int m0 = by * 64, j0 = bx * 64;
  int sr = tid >> 2;
  int sseg = (tid & 3) * 8;
  f4v acc[4][4];
  #pragma unroll
  for (int i = 0; i < 4; ++i)
    #pragma unroll
    for (int j = 0; j < 4; ++j)
      acc[i][j] = (f4v){0.f, 0.f, 0.f, 0.f};

  const u16* a0P = A1 + (size_t)(m0 + sr) * 512 + sseg;
  const u16* b0P0 = W1 + (size_t)(0 * 512 + j0 + sr) * 512 + sseg;
  const u16* b0P1 = W1 + (size_t)(1 * 512 + j0 + sr) * 512 + sseg;
  const u16* b0P2 = W1 + (size_t)(2 * 512 + j0 + sr) * 512 + sseg;
  const u16* b0P3 = W1 + (size_t)(3 * 512 + j0 + sr) * 512 + sseg;
  const u16* a1P  = A2 ? A2 + (size_t)(m0 + sr) * 512 + sseg : a0P;
  const u16* b1P0 = A2 ? W2 + (size_t)(0 * 512 + j0 + sr) * 512 + sseg : b0P0;
  const u16* b1P1 = A2 ? W2 + (size_t)(1 * 512 + j0 + sr) * 512 + sseg : b0P1;
  const u16* b1P2 = A2 ? W2 + (size_t)(2 * 512 + j0 + sr) * 512 + sseg : b0P2;
  const u16* b1P3 = A2 ? W2 + (size_t)(3 * 512 + j0 + sr) * 512 + sseg : b0P3;
  int nit = A2 ? 32 : 16;

  us8v pav, pb0, pb1, pb2, pb3;
  auto LDG = [&](int i){
    int ps = i >> 4, kc = i & 15;
    const u16* ap  = ps ? a1P  : a0P;
    const u16* bp0 = ps ? b1P0 : b0P0;
    const u16* bp1 = ps ? b1P1 : b0P1;
    const u16* bp2 = ps ? b1P2 : b0P2;
    const u16* bp3 = ps ? b1P3 : b0P3;
    pav = *(const us8v*)(ap  + kc * 32);
    pb0 = *(const us8v*)(bp0 + kc * 32);
    pb1 = *(const us8v*)(bp1 + kc * 32);
    pb2 = *(const us8v*)(bp2 + kc * 32);
    pb3 = *(const us8v*)(bp3 + kc * 32);
  };
  LDG(0);
  for (int i = 0; i < nit; ++i){
    __syncthreads();
    *(us8v*)&As[sr * LSTR + sseg]              = pav;
    *(us8v*)&Bs[(0 * 64 + sr) * LSTR + sseg]   = pb0;
    *(us8v*)&Bs[(1 * 64 + sr) * LSTR + sseg]   = pb1;
    *(us8v*)&Bs[(2 * 64 + sr) * LSTR + sseg]   = pb2;
    *(us8v*)&Bs[(3 * 64 + sr) * LSTR + sseg]   = pb3;
    __syncthreads();
    if (i + 1 < nit) LDG(i + 1);
    bf8v af[4], bfr[4];
    #pragma unroll
    for (int mi = 0; mi < 4; ++mi) af[mi]  = *(const bf8v*)&As[(mi * 16 + lm) * LSTR + quad * 8];
    #pragma unroll
    for (int nj = 0; nj < 4; ++nj) bfr[nj] = *(const bf8v*)&Bs[(wave * 64 + nj * 16 + lm) * LSTR + quad * 8];
    #pragma unroll
    for (int mi = 0; mi < 4; ++mi)
      #pragma unroll
      for (int nj = 0; nj < 4; ++nj)
        acc[mi][nj] = __builtin_amdgcn_mfma_f32_16x16x32_bf16(af[mi], bfr[nj], acc[mi][nj], 0, 0, 0);
  }

  float* gL = (float*)Bs;   // [4 gates][16 rows][64 cols] f32 = 16 KB
  #pragma unroll
  for (int mi = 0; mi < 4; ++mi){
    __syncthreads();
    #pragma unroll
    for (int nj = 0; nj < 4; ++nj)
      #pragma unroll
      for (int reg = 0; reg < 4; ++reg)
        gL[wave * 1024 + (quad * 4 + reg) * 64 + nj * 16 + lm] = acc[mi][nj][reg];
    __syncthreads();
    #pragma unroll
    for (int p = 0; p < 4; ++p){
      int idx = p * 256 + tid;
      int bl = idx >> 6, jj = idx & 63;
      int b = m0 + mi * 16 + bl;
      int j = j0 + jj;
      float gi = gL[idx];
      float gf = gL[1024 + idx];
      float gg = gL[2048 + idx];
      float go = gL[3072 + idx];
      if (b1){ gi += b1[j]; gf += b1[512 + j]; gg += b1[1024 + j]; go += b1[1536 + j]; }
      if (b2){ gi += b2[j]; gf += b2[512 + j]; gg += b2[1024 + j]; go += b2[1536 + j]; }
      if (C0){
        const float* cb = C0 + (size_t)b * 2048 + j;
        gi += cb[0]; gf += cb[512]; gg += cb[1024]; go += cb[1536];
      }
      if (Woh){
        int tx = txt[b * 26 + t];
        gi += Woh[(size_t)j * 550 + 512 + tx];
        gf += Woh[(size_t)(512 + j) * 550 + 512 + tx];
        gg += Woh[(size_t)(1024 + j) * 550 + 512 + tx];
        go += Woh[(size_t)(1536 + j) * 550 + 512 + tx];
      }
      float iv = sigm(gi), fv = sigm(gf), gv = tanh_(gg), ov = sigm(go);
      float c = fv * c_io[(size_t)b * 512 + j] + iv * gv;
      float h = ov * tanh_(c);
      c_io[(size_t)b * 512 + j] = c;
      u16 hb = f2bf(h);
      hn[(size_t)b * 512 + j] = hb;
      if (hidout) hidout[((size_t)(b * 26 + t)) * 512 + j] = hb;
    }
  }
}

// ---------------- attention body ----------------
__device__ __forceinline__ void attn_body(float* fsh, int b,
    const u16* __restrict__ fmh, const u16* __restrict__ q,
    const float* __restrict__ sw, const float* __restrict__ sb, u16* __restrict__ ctx)
{
  float* qs  = fsh;          // 512
  float* wss = fsh + 512;    // 512
  float* sA  = fsh + 1024;   // 256
  float* sR  = fsh + 1280;   // 256
  int tid = threadIdx.x;
  qs[tid] = bfs(q[b * 512 + tid]); qs[tid + 256] = bfs(q[b * 512 + 256 + tid]);
  wss[tid] = sw[tid];              wss[tid + 256] = sw[tid + 256];
  __syncthreads();
  const u16* fb = fmh + (size_t)b * 512 * 256;
  float e0 = 0.f, e1 = 0.f, e2 = 0.f, e3 = 0.f;
  for (int c = 0; c < 512; c += 4){
    e0 = fmaf(tanh_(bfs(fb[(c+0)*256 + tid]) + qs[c+0]), wss[c+0], e0);
    e1 = fmaf(tanh_(bfs(fb[(c+1)*256 + tid]) + qs[c+1]), wss[c+1], e1);
    e2 = fmaf(tanh_(bfs(fb[(c+2)*256 + tid]) + qs[c+2]), wss[c+2], e2);
    e3 = fmaf(tanh_(bfs(fb[(c+3)*256 + tid]) + qs[c+3]), wss[c+3], e3);
  }
  float e = (e0 + e1) + (e2 + e3) + sb[0];
  sR[tid] = e; __syncthreads();
  #pragma unroll
  for (int off = 128; off > 0; off >>= 1){
    if (tid < off) sR[tid] = fmaxf(sR[tid], sR[tid + off]);
    __syncthreads();
  }
  float mx = sR[0]; __syncthreads();
  float ex = __expf(e - mx);
  sR[tid] = ex; __syncthreads();
  #pragma unroll
  for (int off = 128; off > 0; off >>= 1){
    if (tid < off) sR[tid] += sR[tid + off];
    __syncthreads();
  }
  float inv = 1.f / sR[0];
  sA[tid] = ex * inv; __syncthreads();
  #pragma unroll
  for (int cc = 0; cc < 2; ++cc){
    int c = tid + cc * 256;
    const u16* row = fb + (size_t)c * 256;
    float s0 = 0.f, s1 = 0.f;
    for (int h8 = 0; h8 < 32; h8 += 2){
      us8v va = *(const us8v*)(row + h8 * 8);
      us8v vb = *(const us8v*)(row + h8 * 8 + 8);
      #pragma unroll
      for (int u2 = 0; u2 < 8; ++u2){
        s0 = fmaf(sA[h8*8 + u2],     bfs(va[u2]), s0);
        s1 = fmaf(sA[h8*8 + 8 + u2], bfs(vb[u2]), s1);
      }
    }
    ctx[(size_t)b * 512 + c] = f2bf(s0 + s1);
  }
  __syncthreads();   // protect fsh before next phase reuse
}

// ---------------- persistent recurrence kernel ----------------
struct RecP {
  const u16* fmh; const u16* Wqc; const float* q_const; u16* qb;
  const u16* r2h; const float* b2c; float* gbuf;
  const float* sw; const float* sb; u16* ctx;
  const u16* r1w; const u16* r1h; const float* r1bi; const float* r1bh;
  const float* Woh; const int* txt;
  const u16* W2c;
  u16 *h1a, *h1b, *h2a, *h2b; float *c1, *c2; u16* hid;
  int* bar;
};

__global__ __launch_bounds__(256, 1) void k_rec(RecP p){
  __shared__ u16 As[64 * LSTR];     // 5120 B
  __shared__ u16 Bs[256 * LSTR];    // 20480 B
  __shared__ float fsh[1536];       // 6144 B
  int blk = blockIdx.x;
  #pragma unroll 1
  for (int t = 0; t < 26; ++t){
    u16* h1i = (t & 1) ? p.h1b : p.h1a;
    u16* h1o = (t & 1) ? p.h1a : p.h1b;
    u16* h2i = (t & 1) ? p.h2b : p.h2a;
    u16* h2o = (t & 1) ? p.h2a : p.h2b;
    // P1: q = q_const + h2@Wqc^T (32 tiles)
    if (blk < 32)
      gemm64(h2i, p.Wqc, nullptr, p.q_const, p.qb, 1, 512,
             (blk >> 3) * 64, (blk & 7) * 64, As, Bs);
    gbar(p.bar);
    // P2: attention (one block per batch)
    attn_body(fsh, blk, p.fmh, p.qb, p.sw, p.sb, p.ctx);
    gbar(p.bar);
    // P3: gates1 + lstm1 (blocks 0..31)  ||  gbuf = h2@r2_whh^T + b2c (blocks 32..159)
    if (blk < 32)
      glstm_body(As, Bs, blk & 7, blk >> 3, p.ctx, p.r1w, h1i, p.r1h,
                 p.r1bi, p.r1bh, nullptr, p.Woh, p.txt, t, h1o, p.c1, nullptr);
    else if (blk < 160){
      int i = blk - 32;
      gemm64(h2i, p.r2h, p.b2c, nullptr, p.gbuf, 0, 2048,
             (i >> 5) * 64, (i & 31) * 64, As, Bs);
    }
    gbar(p.bar);
    // P4: gates2 + lstm2 (1-pass GEMM + gbuf C0)
    if (blk < 32)
      glstm_body(As, Bs, blk & 7, blk >> 3, h1o, p.W2c, nullptr, nullptr,
                 nullptr, nullptr, p.gbuf, nullptr, nullptr, t, h2o, p.c2, p.hid);
    gbar(p.bar);
  }
}

// ---------------- small dense ops ----------------

__global__ __launch_bounds__(256) void k_meanH(const float* __restrict__ H, float* __restrict__ outm){
  int idx = blockIdx.x * 256 + threadIdx.x;  // 256*512
  int b = idx >> 9, k = idx & 511;
  float s = 0.f;
  #pragma unroll
  for (int t = 0; t < 26; ++t) s += H[((size_t)(b * 26 + t)) * 512 + k];
  outm[idx] = s * (1.f / 26.f);
}

__global__ __launch_bounds__(256) void k_pgemm(const float* __restrict__ A, const float* __restrict__ W,
                                               float* __restrict__ out){
  __shared__ float As[32][33];
  __shared__ float Ws[64][33];
  int tid = threadIdx.x;
  int n0 = blockIdx.x * 64, m0 = blockIdx.y * 32;
  float acc[2][4] = {{0.f,0.f,0.f,0.f},{0.f,0.f,0.f,0.f}};
  int ml = (tid >> 4) * 2, nl = (tid & 15) * 4;
  int sm = tid >> 3, sk = (tid & 7) * 4;
  int wn = tid >> 2, wk = (tid & 3) * 8;
  for (int k0 = 0; k0 < 512; k0 += 32){
    __syncthreads();
    float4 av = *(const float4*)&A[(size_t)(m0 + sm) * 512 + k0 + sk];
    As[sm][sk] = av.x; As[sm][sk+1] = av.y; As[sm][sk+2] = av.z; As[sm][sk+3] = av.w;
    const float* wp = W + (size_t)(n0 + wn) * 512 + k0 + wk;
    #pragma unroll
    for (int u2 = 0; u2 < 8; ++u2) Ws[wn][wk + u2] = wp[u2];
    __syncthreads();
    #pragma unroll
    for (int k = 0; k < 32; ++k){
      float a0 = As[ml][k], a1 = As[ml+1][k];
      float w0 = Ws[nl][k], w1 = Ws[nl+1][k], w2 = Ws[nl+2][k], w3 = Ws[nl+3][k];
      acc[0][0] = fmaf(a0,w0,acc[0][0]); acc[0][1] = fmaf(a0,w1,acc[0][1]);
      acc[0][2] = fmaf(a0,w2,acc[0][2]); acc[0][3] = fmaf(a0,w3,acc[0][3]);
      acc[1][0] = fmaf(a1,w0,acc[1][0]); acc[1][1] = fmaf(a1,w1,acc[1][1]);
      acc[1][2] = fmaf(a1,w2,acc[1][2]); acc[1][3] = fmaf(a1,w3,acc[1][3]);
    }
  }
  #pragma unroll
  for (int i = 0; i < 2; ++i)
    #pragma unroll
    for (int j = 0; j < 4; ++j)
      out[(size_t)(m0 + ml + i) * 512 + n0 + nl + j] = acc[i][j];
}

__global__ __launch_bounds__(256) void k_init(const float* __restrict__ hh, const float* __restrict__ hc,
                                              u16* h1, float* c1, u16* h2, float* c2, int* bar){
  int idx = blockIdx.x * 256 + threadIdx.x;  // 131072
  if (idx == 0){ bar[0] = 0; bar[1] = 0; }
  float h0 = 0.5f * (hh[idx] + hh[idx + 131072]);
  float c0 = 0.5f * (hc[idx] + hc[idx + 131072]);
  u16 hb = f2bf(h0);
  h1[idx] = hb; h2[idx] = hb; c1[idx] = c0; c2[idx] = c0;
}

// final projection: out[6656][38] = hid @ genw^T + gen_b. Tile 128x48, grid 52.
__global__ __launch_bounds__(256) void k_gen(const u16* __restrict__ hid,
    const u16* __restrict__ genw, const float* __restrict__ gb, float* __restrict__ out)
{
  __shared__ u16 As[128 * LSTR];
  __shared__ u16 Bs[48 * LSTR];
  int tid = threadIdx.x;
  int wave = tid >> 6, lane = tid & 63;
  int m0 = blockIdx.x * 128;
  int r = tid >> 1, seg = (tid & 1) * 16;
  int lm = lane & 15, quad = lane >> 4;
  int mw = wave * 32;
  f4v acc[2][3];
  #pragma unroll
  for (int i = 0; i < 2; ++i)
    #pragma unroll
    for (int j = 0; j < 3; ++j)
      acc[i][j] = (f4v){0.f, 0.f, 0.f, 0.f};
  const u16* aRow = hid + (size_t)(m0 + r) * 512 + seg;
  const u16* bRow = genw + (size_t)r * 512 + seg;   // valid only tid<96
  us8v pa0 = *(const us8v*)aRow, pa1 = *(const us8v*)(aRow + 8);
  us8v pb0, pb1;
  if (tid < 96){ pb0 = *(const us8v*)bRow; pb1 = *(const us8v*)(bRow + 8); }
  for (int kc = 0; kc < 16; ++kc){
    __syncthreads();
    *(us8v*)&As[r * LSTR + seg]     = pa0;
    *(us8v*)&As[r * LSTR + seg + 8] = pa1;
    if (tid < 96){
      *(us8v*)&Bs[r * LSTR + seg]     = pb0;
      *(us8v*)&Bs[r * LSTR + seg + 8] = pb1;
    }
    __syncthreads();
    if (kc < 15){
      pa0 = *(const us8v*)(aRow + (kc + 1) * 32);
      pa1 = *(const us8v*)(aRow + (kc + 1) * 32 + 8);
      if (tid < 96){
        pb0 = *(const us8v*)(bRow + (kc + 1) * 32);
        pb1 = *(const us8v*)(bRow + (kc + 1) * 32 + 8);
      }
    }
    bf8v af[2], bfr[3];
    #pragma unroll
    for (int i = 0; i < 2; ++i) af[i]  = *(const bf8v*)&As[(mw + i * 16 + lm) * LSTR + quad * 8];
    #pragma unroll
    for (int j = 0; j < 3; ++j) bfr[j] = *(const bf8v*)&Bs[(j * 16 + lm) * LSTR + quad * 8];
    #pragma unroll
    for (int i = 0; i < 2; ++i)
      #pragma unroll
      for (int j = 0; j < 3; ++j)
        acc[i][j] = __builtin_amdgcn_mfma_f32_16x16x32_bf16(af[i], bfr[j], acc[i][j], 0, 0, 0);
  }
  #pragma unroll
  for (int j = 0; j < 3; ++j){
    int n = j * 16 + lm;
    if (n >= 38) continue;
    float bv = gb[n];
    #pragma unroll
    for (int i = 0; i < 2; ++i){
      int mb = m0 + mw + i * 16 + quad * 4;
      #pragma unroll
      for (int reg = 0; reg < 4; ++reg)
        out[(size_t)(mb + reg) * 38 + n] = acc[i][j][reg] + bv;
    }
  }
}

extern "C" void kernel_launch(void* const* d_in, const int* in_sizes, int n_in,
                              void* d_out, int out_size, void* d_ws, size_t ws_size,
                              hipStream_t stream)
{
  (void)in_sizes; (void)n_in; (void)out_size; (void)ws_size;
  const float* fm      = (const float*)d_in[0];
  const float* batchH  = (const float*)d_in[1];
  const float* hh      = (const float*)d_in[2];
  const float* hc      = (const float*)d_in[3];
  const int*   text    = (const int*)d_in[4];
  const float* i2h_w   = (const float*)d_in[5];
  const float* h2h_w   = (const float*)d_in[6];
  const float* h2h_b   = (const float*)d_in[7];
  const float* cm2h_w  = (const float*)d_in[8];
  const float* cm2h_b  = (const float*)d_in[9];
  const float* ch2h_w  = (const float*)d_in[10];
  const float* ch2h_b  = (const float*)d_in[11];
  const float* score_w = (const float*)d_in[12];
  const float* score_b = (const float*)d_in[13];
  const float* r1_wih  = (const float*)d_in[14];
  const float* r1_whh  = (const float*)d_in[15];
  const float* r1_bih  = (const float*)d_in[16];
  const float* r1_bhh  = (const float*)d_in[17];
  const float* hlin_w  = (const float*)d_in[18];
  const float* hlin_b  = (const float*)d_in[19];
  const float* r2_wih  = (const float*)d_in[20];
  const float* r2_whh  = (const float*)d_in[21];
  const float* r2_bih  = (const float*)d_in[22];
  const float* r2_bhh  = (const float*)d_in[23];
  const float* gen_w   = (const float*)d_in[24];
  const float* gen_b   = (const float*)d_in[25];

  // ---- workspace layout (within proven 88.6 MB budget) ----
  char* ws = (char*)d_ws;
  u16* fmh = (u16*)(ws + 0);                 // 67,108,864 B
  char* R  = ws + 67108864;                  // 21,495,808 B multi-phase region
  // conv phase:
  u16* Wt    = (u16*)(R + 0);                // 4,718,592
  u16* chunk = (u16*)(R + 4718592);          // 16,777,216
  // steady-state:
  u16* r1wB  = (u16*)(R + 0);                // 2,097,152
  u16* r1hB  = (u16*)(R + 2097152);          // 2,097,152
  u16* r2hB  = (u16*)(R + 4194304);          // 2,097,152
  u16* W2cB  = (u16*)(R + 6291456);          // 2,097,152
  u16* WqcB  = (u16*)(R + 8388608);          //   524,288
  float* q_const = (float*)(R + 8912896);    //   524,288
  u16* slotA = (u16*)(R + 9437184);          //   262,144  ctx ; genw overlay at epilogue
  u16* qb    = (u16*)(R + 9699328);          //   262,144
  u16* h1a   = (u16*)(R + 9961472);          //   262,144
  u16* h1b   = (u16*)(R + 10223616);         //   262,144
  u16* h2a   = (u16*)(R + 10485760);         //   262,144
  u16* h2b   = (u16*)(R + 10747904);         //   262,144
  float* c1  = (float*)(R + 11010048);       //   524,288
  float* c2  = (float*)(R + 11534336);       //   524,288
  float* b2c = (float*)(R + 12058624);       //     8,192
  float* qbias = (float*)(R + 12066816);     //     2,048
  u16* hid   = (u16*)(R + 12068864);         // 6,815,744 -> ends 18,884,608
  // precompute-only temps (overlay hid; dead before hid written):
  u16* r2wB    = (u16*)(R + 12068864);       // 2,097,152
  u16* hlinT   = (u16*)(R + 14166016);       //   524,288
  u16* h2hT    = (u16*)(R + 14690304);       //   524,288
  u16* ch2hB   = (u16*)(R + 15214592);       //   524,288
  float* bh_mean = (float*)(R + 18884608);   //   524,288 (prologue only)
  float* bh_proj = (float*)(R + 19408896);   //   524,288 (prologue only)
  // recurrence-phase overlay (dead after prologue):
  float* gbuf = (float*)(R + 18884608);      // 2,097,152 -> ends 20,981,760
  int* bar    = (int*)(R + 20981760);        //       128 (grid barrier state)
  u16* genw  = slotA;                        //    49,152 (epilogue overlay)

  // ---- conv phase ----
  k_wt_prep<<<9216, 256, 0, stream>>>(cm2h_w, Wt);
  for (int rb = 0; rb < 4; ++rb){
    k_transpose_fm<<<dim3(4, 8, 64), 256, 0, stream>>>(fm, chunk, rb * 64);
    k_conv<<<512, 256, 0, stream>>>(chunk, Wt, cm2h_b, fmh, rb * 64);
  }
  // ---- weight converts ----
  k_cvt_rw1<<<4096, 256, 0, stream>>>(r1_wih, r1wB);
  k_cvt<<<4096, 256, 0, stream>>>(r1_whh, r1hB, 1048576);
  k_cvt<<<4096, 256, 0, stream>>>(r2_whh, r2hB, 1048576);
  k_cvt<<<4096, 256, 0, stream>>>(r2_wih, r2wB, 1048576);
  k_cvt<<<1024, 256, 0, stream>>>(ch2h_w, ch2hB, 262144);
  k_cvt_t<<<dim3(16, 16), 256, 0, stream>>>(hlin_w, hlinT);
  k_cvt_t<<<dim3(16, 16), 256, 0, stream>>>(h2h_w, h2hT);
  // ---- folded weights ----
  k_mgemm<<<dim3(4, 16), 256, 0, stream>>>(r2wB, hlinT, nullptr, nullptr, W2cB, 1, 512);
  k_mgemm<<<dim3(4, 4), 256, 0, stream>>>(ch2hB, h2hT, nullptr, nullptr, WqcB, 1, 512);
  // ---- prologue ----
  k_meanH<<<512, 256, 0, stream>>>(batchH, bh_mean);
  k_pgemm<<<dim3(8, 8), 256, 0, stream>>>(bh_mean, i2h_w, bh_proj);
  k_bfold<<<2, 256, 0, stream>>>(ch2h_w, h2h_b, ch2h_b, nullptr, qbias, 512);
  k_pgemm<<<dim3(8, 8), 256, 0, stream>>>(bh_proj, ch2h_w, q_const);
  k_addrow<<<512, 256, 0, stream>>>(q_const, qbias);
  k_bfold<<<8, 256, 0, stream>>>(r2_wih, hlin_b, r2_bih, r2_bhh, b2c, 2048);
  k_init<<<512, 256, 0, stream>>>(hh, hc, h1a, c1, h2a, c2, bar);

  // ---- 26-step recurrence: ONE persistent kernel, 4 grid barriers/step ----
  RecP rp;
  rp.fmh = fmh; rp.Wqc = WqcB; rp.q_const = q_const; rp.qb = qb;
  rp.r2h = r2hB; rp.b2c = b2c; rp.gbuf = gbuf;
  rp.sw = score_w; rp.sb = score_b; rp.ctx = slotA;
  rp.r1w = r1wB; rp.r1h = r1hB; rp.r1bi = r1_bih; rp.r1bh = r1_bhh;
  rp.Woh = r1_wih; rp.txt = text; rp.W2c = W2cB;
  rp.h1a = h1a; rp.h1b = h1b; rp.h2a = h2a; rp.h2b = h2b;
  rp.c1 = c1; rp.c2 = c2; rp.hid = hid; rp.bar = bar;
  k_rec<<<256, 256, 0, stream>>>(rp);

  // ---- final projection ----
  k_cvt_gen<<<96, 256, 0, stream>>>(gen_w, genw);
  k_gen<<<52, 256, 0, stream>>>(hid, genw, gen_b, (float*)d_out);
}

// Round 6
// 4847.853 us; speedup vs baseline: 1.8994x; 1.8994x over previous
//
#include <hip/hip_runtime.h>
#include <stdint.h>

typedef unsigned short u16;
typedef unsigned int   u32;
typedef __attribute__((ext_vector_type(8))) short bf8v;          // 8 x bf16 MFMA frag (4 VGPR)
typedef __attribute__((ext_vector_type(4))) float f4v;           // MFMA acc frag
typedef __attribute__((ext_vector_type(8))) unsigned short us8v; // 16B bf16 vector

#define LSTR 40   // padded LDS row stride (u16) for 32-elem bf16 rows

__device__ __forceinline__ float bfs(u16 u){ union { u32 i; float f; } v; v.i = ((u32)u) << 16; return v.f; }
__device__ __forceinline__ u16 f2bf(float f){ union { float f; u32 i; } v; v.f = f; u32 i = v.i; return (u16)((i + 0x7fffu + ((i >> 16) & 1u)) >> 16); }
__device__ __forceinline__ float sigm(float x){ return 1.f / (1.f + __expf(-x)); }
__device__ __forceinline__ float tanh_(float x){ float e = __expf(2.f * x); return 1.f - 2.f / (e + 1.f); }

// ---------------- one-time / chunked prep ----------------

__global__ __launch_bounds__(256) void k_transpose_fm(const float* __restrict__ fm, u16* __restrict__ out, int b_base){
  __shared__ u16 tile[64][65];
  int b = blockIdx.z, hw0 = blockIdx.x * 64, ci0 = blockIdx.y * 64;
  int tid = threadIdx.x;
  int hwl = tid & 63, ci_l = tid >> 6;
  #pragma unroll
  for (int r = 0; r < 16; ++r){
    int ci = ci_l * 16 + r;
    tile[ci][hwl] = f2bf(fm[((size_t)((b_base + b) * 512 + ci0 + ci)) * 256 + hw0 + hwl]);
  }
  __syncthreads();
  int cil = tid & 63, hw_l = tid >> 6;
  #pragma unroll
  for (int r = 0; r < 16; ++r){
    int hw = hw_l * 16 + r;
    out[((size_t)(b * 256 + hw0 + hw)) * 512 + ci0 + cil] = tile[cil][hw];
  }
}

__global__ __launch_bounds__(256) void k_wt_prep(const float* __restrict__ w, u16* __restrict__ wt){
  int idx = blockIdx.x * 256 + threadIdx.x;         // 9*512*512
  int ci = idx & 511, co = (idx >> 9) & 511, dydx = idx >> 18;
  wt[idx] = f2bf(w[((size_t)(co * 512 + ci)) * 9 + dydx]);
}

__global__ __launch_bounds__(256) void k_cvt(const float* __restrict__ src, u16* __restrict__ dst, int n){
  int idx = blockIdx.x * 256 + threadIdx.x;
  if (idx < n) dst[idx] = f2bf(src[idx]);
}
__global__ __launch_bounds__(256) void k_cvt_rw1(const float* __restrict__ src, u16* __restrict__ dst){
  int idx = blockIdx.x * 256 + threadIdx.x;   // 2048*512
  int n = idx >> 9, k = idx & 511;
  dst[idx] = f2bf(src[(size_t)n * 550 + k]);
}
__global__ __launch_bounds__(256) void k_cvt_gen(const float* __restrict__ src, u16* __restrict__ dst){
  int idx = blockIdx.x * 256 + threadIdx.x;   // 48*512
  int n = idx >> 9, k = idx & 511;
  dst[idx] = (n < 38) ? f2bf(src[(size_t)n * 512 + k]) : (u16)0;
}
__global__ __launch_bounds__(256) void k_cvt_t(const float* __restrict__ src, u16* __restrict__ dst){
  __shared__ float tile[32][33];
  int c0 = blockIdx.x * 32, r0 = blockIdx.y * 32;
  int tx = threadIdx.x & 31, ty = threadIdx.x >> 5;
  #pragma unroll
  for (int rr = ty; rr < 32; rr += 8)
    tile[rr][tx] = src[(size_t)(r0 + rr) * 512 + c0 + tx];
  __syncthreads();
  #pragma unroll
  for (int rr = ty; rr < 32; rr += 8)
    dst[(size_t)(c0 + rr) * 512 + r0 + tx] = f2bf(tile[tx][rr]);
}
__global__ __launch_bounds__(256) void k_bfold(const float* __restrict__ W, const float* __restrict__ vin,
    const float* __restrict__ a1, const float* __restrict__ a2, float* __restrict__ out, int N){
  int n = blockIdx.x * 256 + threadIdx.x;
  if (n >= N) return;
  float s = a1 ? a1[n] : 0.f;
  if (a2) s += a2[n];
  const float* wr = W + (size_t)n * 512;
  float acc0 = 0.f, acc1 = 0.f, acc2 = 0.f, acc3 = 0.f;
  for (int k = 0; k < 512; k += 4){
    acc0 = fmaf(wr[k],   vin[k],   acc0);
    acc1 = fmaf(wr[k+1], vin[k+1], acc1);
    acc2 = fmaf(wr[k+2], vin[k+2], acc2);
    acc3 = fmaf(wr[k+3], vin[k+3], acc3);
  }
  out[n] = s + ((acc0 + acc1) + (acc2 + acc3));
}
__global__ __launch_bounds__(256) void k_addrow(float* __restrict__ dst, const float* __restrict__ row){
  int idx = blockIdx.x * 256 + threadIdx.x;  // 131072
  dst[idx] += row[idx & 511];
}

// ---------------- conv3x3 as implicit GEMM (unchanged: control) ----------------
__global__ __launch_bounds__(256) void k_conv(
    const u16* __restrict__ in_t, const u16* __restrict__ Wt,
    const float* __restrict__ cbias, u16* __restrict__ fmh, int b_base)
{
  __shared__ u16 As[128 * LSTR];
  __shared__ u16 Bs[128 * LSTR];
  int tid = threadIdx.x;
  int wave = tid >> 6, lane = tid & 63;
  int nb = blockIdx.x & 3, mb = blockIdx.x >> 2;
  int m0 = mb * 128, n0 = nb * 128;
  int bb = m0 >> 8;
  int r = tid >> 1;
  int seg = (tid & 1) * 16;
  int hwl = (mb & 1) * 128 + r;
  int y = hwl >> 5, x = hwl & 31;
  const u16* aBase = in_t + ((size_t)bb * 256) * 512 + seg;
  const u16* bBase = Wt + ((size_t)(n0 + r)) * 512 + seg;
  int lm = lane & 15, quad = lane >> 4;
  int wm = (wave & 1) * 64, wn = (wave >> 1) * 64;
  f4v acc[4][4];
  #pragma unroll
  for (int i = 0; i < 4; ++i)
    #pragma unroll
    for (int j = 0; j < 4; ++j)
      acc[i][j] = (f4v){0.f, 0.f, 0.f, 0.f};

  us8v pa0, pa1, pb0, pb1;
  auto LDC = [&](int i){
    int dydx = i >> 4, kc = i & 15;
    int dy = dydx / 3, dx = dydx - dy * 3;
    int yy = y + dy - 1, xx = x + dx - 1;
    bool ok = (yy >= 0) && (yy < 8) && (xx >= 0) && (xx < 32);
    const u16* aRow = aBase + (ptrdiff_t)(yy * 32 + xx) * 512 + kc * 32;
    const u16* bRow = bBase + (size_t)dydx * 262144 + kc * 32;
    if (ok){ pa0 = *(const us8v*)aRow; pa1 = *(const us8v*)(aRow + 8); }
    else   { pa0 = (us8v){0,0,0,0,0,0,0,0}; pa1 = pa0; }
    pb0 = *(const us8v*)bRow; pb1 = *(const us8v*)(bRow + 8);
  };
  LDC(0);
  for (int i = 0; i < 144; ++i){
    __syncthreads();
    *(us8v*)&As[r * LSTR + seg]     = pa0;
    *(us8v*)&As[r * LSTR + seg + 8] = pa1;
    *(us8v*)&Bs[r * LSTR + seg]     = pb0;
    *(us8v*)&Bs[r * LSTR + seg + 8] = pb1;
    __syncthreads();
    if (i < 143) LDC(i + 1);
    bf8v af[4], bfr[4];
    #pragma unroll
    for (int ii = 0; ii < 4; ++ii) af[ii]  = *(const bf8v*)&As[(wm + ii * 16 + lm) * LSTR + quad * 8];
    #pragma unroll
    for (int jj = 0; jj < 4; ++jj) bfr[jj] = *(const bf8v*)&Bs[(wn + jj * 16 + lm) * LSTR + quad * 8];
    #pragma unroll
    for (int ii = 0; ii < 4; ++ii)
      #pragma unroll
      for (int jj = 0; jj < 4; ++jj)
        acc[ii][jj] = __builtin_amdgcn_mfma_f32_16x16x32_bf16(af[ii], bfr[jj], acc[ii][jj], 0, 0, 0);
  }
  #pragma unroll
  for (int j = 0; j < 4; ++j){
    int co = n0 + wn + j * 16 + lm;
    float bv = cbias[co];
    #pragma unroll
    for (int i = 0; i < 4; ++i){
      int mrow = m0 + wm + i * 16 + quad * 4;
      int hw = mrow & 255;
      ushort4 pk;
      pk.x = f2bf(acc[i][j][0] + bv);
      pk.y = f2bf(acc[i][j][1] + bv);
      pk.z = f2bf(acc[i][j][2] + bv);
      pk.w = f2bf(acc[i][j][3] + bv);
      *(ushort4*)&fmh[((size_t)((b_base + bb) * 512 + co)) * 256 + hw] = pk;
    }
  }
}

// ---------------- 128x128 GEMM tile body (precompute GEMMs) ----------------
__device__ __forceinline__ void gemm_tile(
    const u16* __restrict__ A, const u16* __restrict__ W,
    const float* __restrict__ b1, const float* __restrict__ C0,
    void* __restrict__ out, int obf16, int N, int m0, int n0,
    u16* As, u16* Bs)
{
  int tid = threadIdx.x;
  int wave = tid >> 6, lane = tid & 63;
  int r = tid >> 1, seg = (tid & 1) * 16;
  int lm = lane & 15, quad = lane >> 4;
  int wm = (wave & 1) * 64, wn = (wave >> 1) * 64;
  f4v acc[4][4];
  #pragma unroll
  for (int i = 0; i < 4; ++i)
    #pragma unroll
    for (int j = 0; j < 4; ++j)
      acc[i][j] = (f4v){0.f, 0.f, 0.f, 0.f};
  const u16* aRow = A + (size_t)(m0 + r) * 512 + seg;
  const u16* bRow = W + (size_t)(n0 + r) * 512 + seg;
  us8v pa0 = *(const us8v*)aRow, pa1 = *(const us8v*)(aRow + 8);
  us8v pb0 = *(const us8v*)bRow, pb1 = *(const us8v*)(bRow + 8);
  for (int kc = 0; kc < 16; ++kc){
    __syncthreads();
    *(us8v*)&As[r * LSTR + seg]     = pa0;
    *(us8v*)&As[r * LSTR + seg + 8] = pa1;
    *(us8v*)&Bs[r * LSTR + seg]     = pb0;
    *(us8v*)&Bs[r * LSTR + seg + 8] = pb1;
    __syncthreads();
    if (kc < 15){
      pa0 = *(const us8v*)(aRow + (kc + 1) * 32);
      pa1 = *(const us8v*)(aRow + (kc + 1) * 32 + 8);
      pb0 = *(const us8v*)(bRow + (kc + 1) * 32);
      pb1 = *(const us8v*)(bRow + (kc + 1) * 32 + 8);
    }
    bf8v af[4], bfr[4];
    #pragma unroll
    for (int i = 0; i < 4; ++i) af[i]  = *(const bf8v*)&As[(wm + i * 16 + lm) * LSTR + quad * 8];
    #pragma unroll
    for (int j = 0; j < 4; ++j) bfr[j] = *(const bf8v*)&Bs[(wn + j * 16 + lm) * LSTR + quad * 8];
    #pragma unroll
    for (int i = 0; i < 4; ++i)
      #pragma unroll
      for (int j = 0; j < 4; ++j)
        acc[i][j] = __builtin_amdgcn_mfma_f32_16x16x32_bf16(af[i], bfr[j], acc[i][j], 0, 0, 0);
  }
  #pragma unroll
  for (int j = 0; j < 4; ++j){
    int n = n0 + wn + j * 16 + lm;
    float badd = b1 ? b1[n] : 0.f;
    #pragma unroll
    for (int i = 0; i < 4; ++i){
      int mb = m0 + wm + i * 16 + quad * 4;
      #pragma unroll
      for (int reg = 0; reg < 4; ++reg){
        int m = mb + reg;
        float v = acc[i][j][reg] + badd;
        if (C0) v += C0[(size_t)m * N + n];
        if (obf16) ((u16*)out)[(size_t)m * N + n] = f2bf(v);
        else       ((float*)out)[(size_t)m * N + n] = v;
      }
    }
  }
}

__global__ __launch_bounds__(256) void k_mgemm(
    const u16* __restrict__ A, const u16* __restrict__ W,
    const float* __restrict__ b1, const float* __restrict__ C0,
    void* __restrict__ out, int obf16, int N)
{
  __shared__ u16 As[128 * LSTR];
  __shared__ u16 Bs[128 * LSTR];
  gemm_tile(A, W, b1, C0, out, obf16, N, blockIdx.y * 128, blockIdx.x * 128, As, Bs);
}

// ---------------- fused gates GEMM + LSTM (pipelined) ----------------
// Block = 64 batches x 64 hidden cols. Wave w computes gate w. grid(8,4)=32.
// OUT gates = A1@W1^T (+A2@W2^T) + b1 + b2 + onehot.
__global__ __launch_bounds__(256, 1) void k_glstm(
    const u16* __restrict__ A1, const u16* __restrict__ W1,
    const u16* __restrict__ A2, const u16* __restrict__ W2,
    const float* __restrict__ b1, const float* __restrict__ b2,
    const float* __restrict__ Woh, const int* __restrict__ txt, int t,
    u16* __restrict__ hn, float* __restrict__ c_io,
    u16* __restrict__ hidout)
{
  __shared__ u16 As[64 * LSTR];    // 5120 B
  __shared__ u16 Bs[256 * LSTR];   // 20480 B (f32 gate-exchange in epilogue, 16 KB used)
  int tid = threadIdx.x;
  int wave = tid >> 6, lane = tid & 63;
  int lm = lane & 15, quad = lane >> 4;
  int m0 = blockIdx.y * 64, j0 = blockIdx.x * 64;
  int sr = tid >> 2;            // 0..63
  int sseg = (tid & 3) * 8;     // u16 offset
  f4v acc[4][4];
  #pragma unroll
  for (int i = 0; i < 4; ++i)
    #pragma unroll
    for (int j = 0; j < 4; ++j)
      acc[i][j] = (f4v){0.f, 0.f, 0.f, 0.f};

  const u16* a0P = A1 + (size_t)(m0 + sr) * 512 + sseg;
  const u16* b0P0 = W1 + (size_t)(0 * 512 + j0 + sr) * 512 + sseg;
  const u16* b0P1 = W1 + (size_t)(1 * 512 + j0 + sr) * 512 + sseg;
  const u16* b0P2 = W1 + (size_t)(2 * 512 + j0 + sr) * 512 + sseg;
  const u16* b0P3 = W1 + (size_t)(3 * 512 + j0 + sr) * 512 + sseg;
  const u16* a1P  = A2 ? A2 + (size_t)(m0 + sr) * 512 + sseg : a0P;
  const u16* b1P0 = A2 ? W2 + (size_t)(0 * 512 + j0 + sr) * 512 + sseg : b0P0;
  const u16* b1P1 = A2 ? W2 + (size_t)(1 * 512 + j0 + sr) * 512 + sseg : b0P1;
  const u16* b1P2 = A2 ? W2 + (size_t)(2 * 512 + j0 + sr) * 512 + sseg : b0P2;
  const u16* b1P3 = A2 ? W2 + (size_t)(3 * 512 + j0 + sr) * 512 + sseg : b0P3;
  int nit = A2 ? 32 : 16;

  us8v pav, pb0, pb1, pb2, pb3;
  auto LDG = [&](int i){
    int ps = i >> 4, kc = i & 15;
    const u16* ap  = ps ? a1P  : a0P;
    const u16* bp0 = ps ? b1P0 : b0P0;
    const u16* bp1 = ps ? b1P1 : b0P1;
    const u16* bp2 = ps ? b1P2 : b0P2;
    const u16* bp3 = ps ? b1P3 : b0P3;
    pav = *(const us8v*)(ap  + kc * 32);
    pb0 = *(const us8v*)(bp0 + kc * 32);
    pb1 = *(const us8v*)(bp1 + kc * 32);
    pb2 = *(const us8v*)(bp2 + kc * 32);
    pb3 = *(const us8v*)(bp3 + kc * 32);
  };
  LDG(0);
  for (int i = 0; i < nit; ++i){
    __syncthreads();
    *(us8v*)&As[sr * LSTR + sseg]              = pav;
    *(us8v*)&Bs[(0 * 64 + sr) * LSTR + sseg]   = pb0;
    *(us8v*)&Bs[(1 * 64 + sr) * LSTR + sseg]   = pb1;
    *(us8v*)&Bs[(2 * 64 + sr) * LSTR + sseg]   = pb2;
    *(us8v*)&Bs[(3 * 64 + sr) * LSTR + sseg]   = pb3;
    __syncthreads();
    if (i + 1 < nit) LDG(i + 1);
    bf8v af[4], bfr[4];
    #pragma unroll
    for (int mi = 0; mi < 4; ++mi) af[mi]  = *(const bf8v*)&As[(mi * 16 + lm) * LSTR + quad * 8];
    #pragma unroll
    for (int nj = 0; nj < 4; ++nj) bfr[nj] = *(const bf8v*)&Bs[(wave * 64 + nj * 16 + lm) * LSTR + quad * 8];
    #pragma unroll
    for (int mi = 0; mi < 4; ++mi)
      #pragma unroll
      for (int nj = 0; nj < 4; ++nj)
        acc[mi][nj] = __builtin_amdgcn_mfma_f32_16x16x32_bf16(af[mi], bfr[nj], acc[mi][nj], 0, 0, 0);
  }

  // epilogue: 4 chunks of 16 batch-rows; gate exchange via LDS; fully unrolled
  float* gL = (float*)Bs;   // [4 gates][16 rows][64 cols] f32 = 16 KB
  #pragma unroll
  for (int mi = 0; mi < 4; ++mi){
    __syncthreads();
    #pragma unroll
    for (int nj = 0; nj < 4; ++nj)
      #pragma unroll
      for (int reg = 0; reg < 4; ++reg)
        gL[wave * 1024 + (quad * 4 + reg) * 64 + nj * 16 + lm] = acc[mi][nj][reg];
    __syncthreads();
    #pragma unroll
    for (int p = 0; p < 4; ++p){
      int idx = p * 256 + tid;          // 16*64 = 1024 outputs
      int bl = idx >> 6, jj = idx & 63;
      int b = m0 + mi * 16 + bl;
      int j = j0 + jj;
      float gi = gL[idx];
      float gf = gL[1024 + idx];
      float gg = gL[2048 + idx];
      float go = gL[3072 + idx];
      if (b1){ gi += b1[j]; gf += b1[512 + j]; gg += b1[1024 + j]; go += b1[1536 + j]; }
      if (b2){ gi += b2[j]; gf += b2[512 + j]; gg += b2[1024 + j]; go += b2[1536 + j]; }
      if (Woh){
        int tx = txt[b * 26 + t];
        gi += Woh[(size_t)j * 550 + 512 + tx];
        gf += Woh[(size_t)(512 + j) * 550 + 512 + tx];
        gg += Woh[(size_t)(1024 + j) * 550 + 512 + tx];
        go += Woh[(size_t)(1536 + j) * 550 + 512 + tx];
      }
      float iv = sigm(gi), fv = sigm(gf), gv = tanh_(gg), ov = sigm(go);
      float c = fv * c_io[(size_t)b * 512 + j] + iv * gv;
      float h = ov * tanh_(c);
      c_io[(size_t)b * 512 + j] = c;
      u16 hb = f2bf(h);
      hn[(size_t)b * 512 + j] = hb;
      if (hidout) hidout[((size_t)(b * 26 + t)) * 512 + j] = hb;
    }
  }
}

// ---------------- small dense ops ----------------

__global__ __launch_bounds__(256) void k_meanH(const float* __restrict__ H, float* __restrict__ outm){
  int idx = blockIdx.x * 256 + threadIdx.x;  // 256*512
  int b = idx >> 9, k = idx & 511;
  float s = 0.f;
  #pragma unroll
  for (int t = 0; t < 26; ++t) s += H[((size_t)(b * 26 + t)) * 512 + k];
  outm[idx] = s * (1.f / 26.f);
}

__global__ __launch_bounds__(256) void k_pgemm(const float* __restrict__ A, const float* __restrict__ W,
                                               float* __restrict__ out){
  __shared__ float As[32][33];
  __shared__ float Ws[64][33];
  int tid = threadIdx.x;
  int n0 = blockIdx.x * 64, m0 = blockIdx.y * 32;
  float acc[2][4] = {{0.f,0.f,0.f,0.f},{0.f,0.f,0.f,0.f}};
  int ml = (tid >> 4) * 2, nl = (tid & 15) * 4;
  int sm = tid >> 3, sk = (tid & 7) * 4;
  int wn = tid >> 2, wk = (tid & 3) * 8;
  for (int k0 = 0; k0 < 512; k0 += 32){
    __syncthreads();
    float4 av = *(const float4*)&A[(size_t)(m0 + sm) * 512 + k0 + sk];
    As[sm][sk] = av.x; As[sm][sk+1] = av.y; As[sm][sk+2] = av.z; As[sm][sk+3] = av.w;
    const float* wp = W + (size_t)(n0 + wn) * 512 + k0 + wk;
    #pragma unroll
    for (int u2 = 0; u2 < 8; ++u2) Ws[wn][wk + u2] = wp[u2];
    __syncthreads();
    #pragma unroll
    for (int k = 0; k < 32; ++k){
      float a0 = As[ml][k], a1 = As[ml+1][k];
      float w0 = Ws[nl][k], w1 = Ws[nl+1][k], w2 = Ws[nl+2][k], w3 = Ws[nl+3][k];
      acc[0][0] = fmaf(a0,w0,acc[0][0]); acc[0][1] = fmaf(a0,w1,acc[0][1]);
      acc[0][2] = fmaf(a0,w2,acc[0][2]); acc[0][3] = fmaf(a0,w3,acc[0][3]);
      acc[1][0] = fmaf(a1,w0,acc[1][0]); acc[1][1] = fmaf(a1,w1,acc[1][1]);
      acc[1][2] = fmaf(a1,w2,acc[1][2]); acc[1][3] = fmaf(a1,w3,acc[1][3]);
    }
  }
  #pragma unroll
  for (int i = 0; i < 2; ++i)
    #pragma unroll
    for (int j = 0; j < 4; ++j)
      out[(size_t)(m0 + ml + i) * 512 + n0 + nl + j] = acc[i][j];
}

__global__ __launch_bounds__(256) void k_init(const float* __restrict__ hh, const float* __restrict__ hc,
                                              u16* h1, float* c1, u16* h2, float* c2){
  int idx = blockIdx.x * 256 + threadIdx.x;  // 131072
  float h0 = 0.5f * (hh[idx] + hh[idx + 131072]);
  float c0 = 0.5f * (hc[idx] + hc[idx + 131072]);
  u16 hb = f2bf(h0);
  h1[idx] = hb; h2[idx] = hb; c1[idx] = c0; c2[idx] = c0;
}

// fused q-matvec + attention: one block per batch.
// q[n] = q_const[b][n] + sum_m Wqc[n][m]*h2[b][m]  (f32, in-block)
// then e -> softmax -> context, ctx bf16 out.
__global__ __launch_bounds__(256) void k_attnq(const u16* __restrict__ fmh,
    const u16* __restrict__ h2, const u16* __restrict__ Wqc, const float* __restrict__ q_const,
    const float* __restrict__ sw, const float* __restrict__ sb, u16* __restrict__ ctx)
{
  __shared__ float qs[512], wss[512], hsh[512], sA[256], sR[256];
  int b = blockIdx.x, tid = threadIdx.x;
  hsh[tid]       = bfs(h2[b * 512 + tid]);
  hsh[tid + 256] = bfs(h2[b * 512 + 256 + tid]);
  wss[tid] = sw[tid]; wss[tid + 256] = sw[tid + 256];
  __syncthreads();
  // q matvec: thread handles n = tid and n = tid+256. All threads walk m together
  // -> LDS broadcast on hsh; Wqc rows are contiguous bf16 (L2-resident).
  #pragma unroll
  for (int half = 0; half < 2; ++half){
    int n = tid + half * 256;
    const u16* wr = Wqc + (size_t)n * 512;
    float a0 = 0.f, a1 = 0.f, a2 = 0.f, a3 = 0.f;
    for (int m = 0; m < 512; m += 16){
      us8v w0 = *(const us8v*)(wr + m);
      us8v w1 = *(const us8v*)(wr + m + 8);
      a0 = fmaf(bfs(w0[0]), hsh[m+0], a0);  a1 = fmaf(bfs(w0[1]), hsh[m+1], a1);
      a2 = fmaf(bfs(w0[2]), hsh[m+2], a2);  a3 = fmaf(bfs(w0[3]), hsh[m+3], a3);
      a0 = fmaf(bfs(w0[4]), hsh[m+4], a0);  a1 = fmaf(bfs(w0[5]), hsh[m+5], a1);
      a2 = fmaf(bfs(w0[6]), hsh[m+6], a2);  a3 = fmaf(bfs(w0[7]), hsh[m+7], a3);
      a0 = fmaf(bfs(w1[0]), hsh[m+8], a0);  a1 = fmaf(bfs(w1[1]), hsh[m+9], a1);
      a2 = fmaf(bfs(w1[2]), hsh[m+10], a2); a3 = fmaf(bfs(w1[3]), hsh[m+11], a3);
      a0 = fmaf(bfs(w1[4]), hsh[m+12], a0); a1 = fmaf(bfs(w1[5]), hsh[m+13], a1);
      a2 = fmaf(bfs(w1[6]), hsh[m+14], a2); a3 = fmaf(bfs(w1[7]), hsh[m+15], a3);
    }
    qs[n] = q_const[(size_t)b * 512 + n] + ((a0 + a1) + (a2 + a3));
  }
  __syncthreads();
  const u16* fb = fmh + (size_t)b * 512 * 256;
  float e0 = 0.f, e1 = 0.f, e2 = 0.f, e3 = 0.f;
  for (int c = 0; c < 512; c += 4){
    e0 = fmaf(tanh_(bfs(fb[(c+0)*256 + tid]) + qs[c+0]), wss[c+0], e0);
    e1 = fmaf(tanh_(bfs(fb[(c+1)*256 + tid]) + qs[c+1]), wss[c+1], e1);
    e2 = fmaf(tanh_(bfs(fb[(c+2)*256 + tid]) + qs[c+2]), wss[c+2], e2);
    e3 = fmaf(tanh_(bfs(fb[(c+3)*256 + tid]) + qs[c+3]), wss[c+3], e3);
  }
  float e = (e0 + e1) + (e2 + e3) + sb[0];
  sR[tid] = e; __syncthreads();
  #pragma unroll
  for (int off = 128; off > 0; off >>= 1){
    if (tid < off) sR[tid] = fmaxf(sR[tid], sR[tid + off]);
    __syncthreads();
  }
  float mx = sR[0]; __syncthreads();
  float ex = __expf(e - mx);
  sR[tid] = ex; __syncthreads();
  #pragma unroll
  for (int off = 128; off > 0; off >>= 1){
    if (tid < off) sR[tid] += sR[tid + off];
    __syncthreads();
  }
  float inv = 1.f / sR[0];
  sA[tid] = ex * inv; __syncthreads();
  #pragma unroll
  for (int cc = 0; cc < 2; ++cc){
    int c = tid + cc * 256;
    const u16* row = fb + (size_t)c * 256;
    float s0 = 0.f, s1 = 0.f;
    for (int h8 = 0; h8 < 32; h8 += 2){
      us8v va = *(const us8v*)(row + h8 * 8);
      us8v vb = *(const us8v*)(row + h8 * 8 + 8);
      #pragma unroll
      for (int u2 = 0; u2 < 8; ++u2){
        s0 = fmaf(sA[h8*8 + u2],     bfs(va[u2]), s0);
        s1 = fmaf(sA[h8*8 + 8 + u2], bfs(vb[u2]), s1);
      }
    }
    ctx[(size_t)b * 512 + c] = f2bf(s0 + s1);
  }
}

// final projection: out[6656][38] = hid @ genw^T + gen_b. Tile 128x48, grid 52.
__global__ __launch_bounds__(256) void k_gen(const u16* __restrict__ hid,
    const u16* __restrict__ genw, const float* __restrict__ gb, float* __restrict__ out)
{
  __shared__ u16 As[128 * LSTR];
  __shared__ u16 Bs[48 * LSTR];
  int tid = threadIdx.x;
  int wave = tid >> 6, lane = tid & 63;
  int m0 = blockIdx.x * 128;
  int r = tid >> 1, seg = (tid & 1) * 16;
  int lm = lane & 15, quad = lane >> 4;
  int mw = wave * 32;
  f4v acc[2][3];
  #pragma unroll
  for (int i = 0; i < 2; ++i)
    #pragma unroll
    for (int j = 0; j < 3; ++j)
      acc[i][j] = (f4v){0.f, 0.f, 0.f, 0.f};
  const u16* aRow = hid + (size_t)(m0 + r) * 512 + seg;
  const u16* bRow = genw + (size_t)r * 512 + seg;   // valid only tid<96
  us8v pa0 = *(const us8v*)aRow, pa1 = *(const us8v*)(aRow + 8);
  us8v pb0, pb1;
  if (tid < 96){ pb0 = *(const us8v*)bRow; pb1 = *(const us8v*)(bRow + 8); }
  for (int kc = 0; kc < 16; ++kc){
    __syncthreads();
    *(us8v*)&As[r * LSTR + seg]     = pa0;
    *(us8v*)&As[r * LSTR + seg + 8] = pa1;
    if (tid < 96){
      *(us8v*)&Bs[r * LSTR + seg]     = pb0;
      *(us8v*)&Bs[r * LSTR + seg + 8] = pb1;
    }
    __syncthreads();
    if (kc < 15){
      pa0 = *(const us8v*)(aRow + (kc + 1) * 32);
      pa1 = *(const us8v*)(aRow + (kc + 1) * 32 + 8);
      if (tid < 96){
        pb0 = *(const us8v*)(bRow + (kc + 1) * 32);
        pb1 = *(const us8v*)(bRow + (kc + 1) * 32 + 8);
      }
    }
    bf8v af[2], bfr[3];
    #pragma unroll
    for (int i = 0; i < 2; ++i) af[i]  = *(const bf8v*)&As[(mw + i * 16 + lm) * LSTR + quad * 8];
    #pragma unroll
    for (int j = 0; j < 3; ++j) bfr[j] = *(const bf8v*)&Bs[(j * 16 + lm) * LSTR + quad * 8];
    #pragma unroll
    for (int i = 0; i < 2; ++i)
      #pragma unroll
      for (int j = 0; j < 3; ++j)
        acc[i][j] = __builtin_amdgcn_mfma_f32_16x16x32_bf16(af[i], bfr[j], acc[i][j], 0, 0, 0);
  }
  #pragma unroll
  for (int j = 0; j < 3; ++j){
    int n = j * 16 + lm;
    if (n >= 38) continue;
    float bv = gb[n];
    #pragma unroll
    for (int i = 0; i < 2; ++i){
      int mb = m0 + mw + i * 16 + quad * 4;
      #pragma unroll
      for (int reg = 0; reg < 4; ++reg)
        out[(size_t)(mb + reg) * 38 + n] = acc[i][j][reg] + bv;
    }
  }
}

extern "C" void kernel_launch(void* const* d_in, const int* in_sizes, int n_in,
                              void* d_out, int out_size, void* d_ws, size_t ws_size,
                              hipStream_t stream)
{
  (void)in_sizes; (void)n_in; (void)out_size; (void)ws_size;
  const float* fm      = (const float*)d_in[0];
  const float* batchH  = (const float*)d_in[1];
  const float* hh      = (const float*)d_in[2];
  const float* hc      = (const float*)d_in[3];
  const int*   text    = (const int*)d_in[4];
  const float* i2h_w   = (const float*)d_in[5];
  const float* h2h_w   = (const float*)d_in[6];
  const float* h2h_b   = (const float*)d_in[7];
  const float* cm2h_w  = (const float*)d_in[8];
  const float* cm2h_b  = (const float*)d_in[9];
  const float* ch2h_w  = (const float*)d_in[10];
  const float* ch2h_b  = (const float*)d_in[11];
  const float* score_w = (const float*)d_in[12];
  const float* score_b = (const float*)d_in[13];
  const float* r1_wih  = (const float*)d_in[14];
  const float* r1_whh  = (const float*)d_in[15];
  const float* r1_bih  = (const float*)d_in[16];
  const float* r1_bhh  = (const float*)d_in[17];
  const float* hlin_w  = (const float*)d_in[18];
  const float* hlin_b  = (const float*)d_in[19];
  const float* r2_wih  = (const float*)d_in[20];
  const float* r2_whh  = (const float*)d_in[21];
  const float* r2_bih  = (const float*)d_in[22];
  const float* r2_bhh  = (const float*)d_in[23];
  const float* gen_w   = (const float*)d_in[24];
  const float* gen_b   = (const float*)d_in[25];

  // ---- workspace layout (within proven 88.6 MB budget) ----
  char* ws = (char*)d_ws;
  u16* fmh = (u16*)(ws + 0);                 // 67,108,864 B
  char* R  = ws + 67108864;                  // 21,495,808 B multi-phase region
  // conv phase:
  u16* Wt    = (u16*)(R + 0);                // 4,718,592
  u16* chunk = (u16*)(R + 4718592);          // 16,777,216
  // steady-state:
  u16* r1wB  = (u16*)(R + 0);                // 2,097,152
  u16* r1hB  = (u16*)(R + 2097152);          // 2,097,152
  u16* r2hB  = (u16*)(R + 4194304);          // 2,097,152
  u16* W2cB  = (u16*)(R + 6291456);          // 2,097,152
  u16* WqcB  = (u16*)(R + 8388608);          //   524,288
  float* q_const = (float*)(R + 8912896);    //   524,288
  u16* slotA = (u16*)(R + 9437184);          //   262,144  ctx ; genw overlay at epilogue
  u16* h1a   = (u16*)(R + 9961472);          //   262,144
  u16* h1b   = (u16*)(R + 10223616);         //   262,144
  u16* h2a   = (u16*)(R + 10485760);         //   262,144
  u16* h2b   = (u16*)(R + 10747904);         //   262,144
  float* c1  = (float*)(R + 11010048);       //   524,288
  float* c2  = (float*)(R + 11534336);       //   524,288
  float* b2c = (float*)(R + 12058624);       //     8,192
  float* qbias = (float*)(R + 12066816);     //     2,048
  u16* hid   = (u16*)(R + 12068864);         // 6,815,744 -> ends 18,884,608
  // precompute-only temps (overlay hid; dead before hid written):
  u16* r2wB    = (u16*)(R + 12068864);       // 2,097,152
  u16* hlinT   = (u16*)(R + 14166016);       //   524,288
  u16* h2hT    = (u16*)(R + 14690304);       //   524,288
  u16* ch2hB   = (u16*)(R + 15214592);       //   524,288
  float* bh_mean = (float*)(R + 18884608);   //   524,288 (prologue only)
  float* bh_proj = (float*)(R + 19408896);   //   524,288 (prologue only)
  u16* genw  = slotA;                        //    49,152 (epilogue overlay)

  // ---- conv phase ----
  k_wt_prep<<<9216, 256, 0, stream>>>(cm2h_w, Wt);
  for (int rb = 0; rb < 4; ++rb){
    k_transpose_fm<<<dim3(4, 8, 64), 256, 0, stream>>>(fm, chunk, rb * 64);
    k_conv<<<512, 256, 0, stream>>>(chunk, Wt, cm2h_b, fmh, rb * 64);
  }
  // ---- weight converts ----
  k_cvt_rw1<<<4096, 256, 0, stream>>>(r1_wih, r1wB);
  k_cvt<<<4096, 256, 0, stream>>>(r1_whh, r1hB, 1048576);
  k_cvt<<<4096, 256, 0, stream>>>(r2_whh, r2hB, 1048576);
  k_cvt<<<4096, 256, 0, stream>>>(r2_wih, r2wB, 1048576);
  k_cvt<<<1024, 256, 0, stream>>>(ch2h_w, ch2hB, 262144);
  k_cvt_t<<<dim3(16, 16), 256, 0, stream>>>(hlin_w, hlinT);
  k_cvt_t<<<dim3(16, 16), 256, 0, stream>>>(h2h_w, h2hT);
  // ---- folded weights ----
  k_mgemm<<<dim3(4, 16), 256, 0, stream>>>(r2wB, hlinT, nullptr, nullptr, W2cB, 1, 512);
  k_mgemm<<<dim3(4, 4), 256, 0, stream>>>(ch2hB, h2hT, nullptr, nullptr, WqcB, 1, 512);
  // ---- prologue ----
  k_meanH<<<512, 256, 0, stream>>>(batchH, bh_mean);
  k_pgemm<<<dim3(8, 8), 256, 0, stream>>>(bh_mean, i2h_w, bh_proj);
  k_bfold<<<2, 256, 0, stream>>>(ch2h_w, h2h_b, ch2h_b, nullptr, qbias, 512);
  k_pgemm<<<dim3(8, 8), 256, 0, stream>>>(bh_proj, ch2h_w, q_const);
  k_addrow<<<512, 256, 0, stream>>>(q_const, qbias);
  k_bfold<<<8, 256, 0, stream>>>(r2_wih, hlin_b, r2_bih, r2_bhh, b2c, 2048);
  k_init<<<512, 256, 0, stream>>>(hh, hc, h1a, c1, h2a, c2);

  // ---- 26-step recurrence: 3 kernels/step ----
  for (int t = 0; t < 26; ++t){
    u16* h1i = (t & 1) ? h1b : h1a;
    u16* h1o = (t & 1) ? h1a : h1b;
    u16* h2i = (t & 1) ? h2b : h2a;
    u16* h2o = (t & 1) ? h2a : h2b;
    // q (in-block matvec) + attention -> ctx in slotA (bf16)
    k_attnq<<<256, 256, 0, stream>>>(fmh, h2i, WqcB, q_const, score_w, score_b, slotA);
    // gates1+lstm1 (2-pass): ctx@r1w^T + h1@r1h^T + biases + onehot -> h1o, c1
    k_glstm<<<dim3(8, 4), 256, 0, stream>>>(slotA, r1wB, h1i, r1hB,
        r1_bih, r1_bhh, r1_wih, text, t, h1o, c1, nullptr);
    // gates2+lstm2 (2-pass): h1o@W2c^T + h2i@r2_whh^T + b2c -> h2o, c2, hid
    k_glstm<<<dim3(8, 4), 256, 0, stream>>>(h1o, W2cB, h2i, r2hB,
        b2c, nullptr, nullptr, nullptr, t, h2o, c2, hid);
  }
  // ---- final projection ----
  k_cvt_gen<<<96, 256, 0, stream>>>(gen_w, genw);
  k_gen<<<52, 256, 0, stream>>>(hid, genw, gen_b, (float*)d_out);
}

// Round 7
// 4184.620 us; speedup vs baseline: 2.2004x; 1.1585x over previous
//
#include <hip/hip_runtime.h>
#include <stdint.h>

typedef unsigned short u16;
typedef unsigned int   u32;
typedef __attribute__((ext_vector_type(8))) short bf8v;          // 8 x bf16 MFMA frag (4 VGPR)
typedef __attribute__((ext_vector_type(4))) float f4v;           // MFMA acc frag
typedef __attribute__((ext_vector_type(8))) unsigned short us8v; // 16B bf16 vector

#define LSTR 40   // padded LDS row stride (u16) for 32-elem bf16 rows

__device__ __forceinline__ float bfs(u16 u){ union { u32 i; float f; } v; v.i = ((u32)u) << 16; return v.f; }
__device__ __forceinline__ u16 f2bf(float f){ union { float f; u32 i; } v; v.f = f; u32 i = v.i; return (u16)((i + 0x7fffu + ((i >> 16) & 1u)) >> 16); }
__device__ __forceinline__ float sigm(float x){ return 1.f / (1.f + __expf(-x)); }
__device__ __forceinline__ float tanh_(float x){ float e = __expf(2.f * x); return 1.f - 2.f / (e + 1.f); }

// ---------------- one-time / chunked prep ----------------

__global__ __launch_bounds__(256) void k_transpose_fm(const float* __restrict__ fm, u16* __restrict__ out, int b_base){
  __shared__ u16 tile[64][65];
  int b = blockIdx.z, hw0 = blockIdx.x * 64, ci0 = blockIdx.y * 64;
  int tid = threadIdx.x;
  int hwl = tid & 63, ci_l = tid >> 6;
  #pragma unroll
  for (int r = 0; r < 16; ++r){
    int ci = ci_l * 16 + r;
    tile[ci][hwl] = f2bf(fm[((size_t)((b_base + b) * 512 + ci0 + ci)) * 256 + hw0 + hwl]);
  }
  __syncthreads();
  int cil = tid & 63, hw_l = tid >> 6;
  #pragma unroll
  for (int r = 0; r < 16; ++r){
    int hw = hw_l * 16 + r;
    out[((size_t)(b * 256 + hw0 + hw)) * 512 + ci0 + cil] = tile[cil][hw];
  }
}

__global__ __launch_bounds__(256) void k_wt_prep(const float* __restrict__ w, u16* __restrict__ wt){
  int idx = blockIdx.x * 256 + threadIdx.x;         // 9*512*512
  int ci = idx & 511, co = (idx >> 9) & 511, dydx = idx >> 18;
  wt[idx] = f2bf(w[((size_t)(co * 512 + ci)) * 9 + dydx]);
}

__global__ __launch_bounds__(256) void k_cvt(const float* __restrict__ src, u16* __restrict__ dst, int n){
  int idx = blockIdx.x * 256 + threadIdx.x;
  if (idx < n) dst[idx] = f2bf(src[idx]);
}
__global__ __launch_bounds__(256) void k_cvt_rw1(const float* __restrict__ src, u16* __restrict__ dst){
  int idx = blockIdx.x * 256 + threadIdx.x;   // 2048*512
  int n = idx >> 9, k = idx & 511;
  dst[idx] = f2bf(src[(size_t)n * 550 + k]);
}
__global__ __launch_bounds__(256) void k_cvt_gen(const float* __restrict__ src, u16* __restrict__ dst){
  int idx = blockIdx.x * 256 + threadIdx.x;   // 48*512
  int n = idx >> 9, k = idx & 511;
  dst[idx] = (n < 38) ? f2bf(src[(size_t)n * 512 + k]) : (u16)0;
}
__global__ __launch_bounds__(256) void k_cvt_t(const float* __restrict__ src, u16* __restrict__ dst){
  __shared__ float tile[32][33];
  int c0 = blockIdx.x * 32, r0 = blockIdx.y * 32;
  int tx = threadIdx.x & 31, ty = threadIdx.x >> 5;
  #pragma unroll
  for (int rr = ty; rr < 32; rr += 8)
    tile[rr][tx] = src[(size_t)(r0 + rr) * 512 + c0 + tx];
  __syncthreads();
  #pragma unroll
  for (int rr = ty; rr < 32; rr += 8)
    dst[(size_t)(c0 + rr) * 512 + r0 + tx] = f2bf(tile[tx][rr]);
}
__global__ __launch_bounds__(256) void k_bfold(const float* __restrict__ W, const float* __restrict__ vin,
    const float* __restrict__ a1, const float* __restrict__ a2, float* __restrict__ out, int N){
  int n = blockIdx.x * 256 + threadIdx.x;
  if (n >= N) return;
  float s = a1 ? a1[n] : 0.f;
  if (a2) s += a2[n];
  const float* wr = W + (size_t)n * 512;
  float acc0 = 0.f, acc1 = 0.f, acc2 = 0.f, acc3 = 0.f;
  for (int k = 0; k < 512; k += 4){
    acc0 = fmaf(wr[k],   vin[k],   acc0);
    acc1 = fmaf(wr[k+1], vin[k+1], acc1);
    acc2 = fmaf(wr[k+2], vin[k+2], acc2);
    acc3 = fmaf(wr[k+3], vin[k+3], acc3);
  }
  out[n] = s + ((acc0 + acc1) + (acc2 + acc3));
}
__global__ __launch_bounds__(256) void k_addrow(float* __restrict__ dst, const float* __restrict__ row){
  int idx = blockIdx.x * 256 + threadIdx.x;  // 131072
  dst[idx] += row[idx & 511];
}

// ---------------- conv3x3 as implicit GEMM (unchanged: control) ----------------
__global__ __launch_bounds__(256) void k_conv(
    const u16* __restrict__ in_t, const u16* __restrict__ Wt,
    const float* __restrict__ cbias, u16* __restrict__ fmh, int b_base)
{
  __shared__ u16 As[128 * LSTR];
  __shared__ u16 Bs[128 * LSTR];
  int tid = threadIdx.x;
  int wave = tid >> 6, lane = tid & 63;
  int nb = blockIdx.x & 3, mb = blockIdx.x >> 2;
  int m0 = mb * 128, n0 = nb * 128;
  int bb = m0 >> 8;
  int r = tid >> 1;
  int seg = (tid & 1) * 16;
  int hwl = (mb & 1) * 128 + r;
  int y = hwl >> 5, x = hwl & 31;
  const u16* aBase = in_t + ((size_t)bb * 256) * 512 + seg;
  const u16* bBase = Wt + ((size_t)(n0 + r)) * 512 + seg;
  int lm = lane & 15, quad = lane >> 4;
  int wm = (wave & 1) * 64, wn = (wave >> 1) * 64;
  f4v acc[4][4];
  #pragma unroll
  for (int i = 0; i < 4; ++i)
    #pragma unroll
    for (int j = 0; j < 4; ++j)
      acc[i][j] = (f4v){0.f, 0.f, 0.f, 0.f};

  us8v pa0, pa1, pb0, pb1;
  auto LDC = [&](int i){
    int dydx = i >> 4, kc = i & 15;
    int dy = dydx / 3, dx = dydx - dy * 3;
    int yy = y + dy - 1, xx = x + dx - 1;
    bool ok = (yy >= 0) && (yy < 8) && (xx >= 0) && (xx < 32);
    const u16* aRow = aBase + (ptrdiff_t)(yy * 32 + xx) * 512 + kc * 32;
    const u16* bRow = bBase + (size_t)dydx * 262144 + kc * 32;
    if (ok){ pa0 = *(const us8v*)aRow; pa1 = *(const us8v*)(aRow + 8); }
    else   { pa0 = (us8v){0,0,0,0,0,0,0,0}; pa1 = pa0; }
    pb0 = *(const us8v*)bRow; pb1 = *(const us8v*)(bRow + 8);
  };
  LDC(0);
  for (int i = 0; i < 144; ++i){
    __syncthreads();
    *(us8v*)&As[r * LSTR + seg]     = pa0;
    *(us8v*)&As[r * LSTR + seg + 8] = pa1;
    *(us8v*)&Bs[r * LSTR + seg]     = pb0;
    *(us8v*)&Bs[r * LSTR + seg + 8] = pb1;
    __syncthreads();
    if (i < 143) LDC(i + 1);
    bf8v af[4], bfr[4];
    #pragma unroll
    for (int ii = 0; ii < 4; ++ii) af[ii]  = *(const bf8v*)&As[(wm + ii * 16 + lm) * LSTR + quad * 8];
    #pragma unroll
    for (int jj = 0; jj < 4; ++jj) bfr[jj] = *(const bf8v*)&Bs[(wn + jj * 16 + lm) * LSTR + quad * 8];
    #pragma unroll
    for (int ii = 0; ii < 4; ++ii)
      #pragma unroll
      for (int jj = 0; jj < 4; ++jj)
        acc[ii][jj] = __builtin_amdgcn_mfma_f32_16x16x32_bf16(af[ii], bfr[jj], acc[ii][jj], 0, 0, 0);
  }
  #pragma unroll
  for (int j = 0; j < 4; ++j){
    int co = n0 + wn + j * 16 + lm;
    float bv = cbias[co];
    #pragma unroll
    for (int i = 0; i < 4; ++i){
      int mrow = m0 + wm + i * 16 + quad * 4;
      int hw = mrow & 255;
      ushort4 pk;
      pk.x = f2bf(acc[i][j][0] + bv);
      pk.y = f2bf(acc[i][j][1] + bv);
      pk.z = f2bf(acc[i][j][2] + bv);
      pk.w = f2bf(acc[i][j][3] + bv);
      *(ushort4*)&fmh[((size_t)((b_base + bb) * 512 + co)) * 256 + hw] = pk;
    }
  }
}

// ---------------- 128x128 GEMM tile body (precompute GEMMs) ----------------
__device__ __forceinline__ void gemm_tile(
    const u16* __restrict__ A, const u16* __restrict__ W,
    const float* __restrict__ b1, const float* __restrict__ C0,
    void* __restrict__ out, int obf16, int N, int m0, int n0,
    u16* As, u16* Bs)
{
  int tid = threadIdx.x;
  int wave = tid >> 6, lane = tid & 63;
  int r = tid >> 1, seg = (tid & 1) * 16;
  int lm = lane & 15, quad = lane >> 4;
  int wm = (wave & 1) * 64, wn = (wave >> 1) * 64;
  f4v acc[4][4];
  #pragma unroll
  for (int i = 0; i < 4; ++i)
    #pragma unroll
    for (int j = 0; j < 4; ++j)
      acc[i][j] = (f4v){0.f, 0.f, 0.f, 0.f};
  const u16* aRow = A + (size_t)(m0 + r) * 512 + seg;
  const u16* bRow = W + (size_t)(n0 + r) * 512 + seg;
  us8v pa0 = *(const us8v*)aRow, pa1 = *(const us8v*)(aRow + 8);
  us8v pb0 = *(const us8v*)bRow, pb1 = *(const us8v*)(bRow + 8);
  for (int kc = 0; kc < 16; ++kc){
    __syncthreads();
    *(us8v*)&As[r * LSTR + seg]     = pa0;
    *(us8v*)&As[r * LSTR + seg + 8] = pa1;
    *(us8v*)&Bs[r * LSTR + seg]     = pb0;
    *(us8v*)&Bs[r * LSTR + seg + 8] = pb1;
    __syncthreads();
    if (kc < 15){
      pa0 = *(const us8v*)(aRow + (kc + 1) * 32);
      pa1 = *(const us8v*)(aRow + (kc + 1) * 32 + 8);
      pb0 = *(const us8v*)(bRow + (kc + 1) * 32);
      pb1 = *(const us8v*)(bRow + (kc + 1) * 32 + 8);
    }
    bf8v af[4], bfr[4];
    #pragma unroll
    for (int i = 0; i < 4; ++i) af[i]  = *(const bf8v*)&As[(wm + i * 16 + lm) * LSTR + quad * 8];
    #pragma unroll
    for (int j = 0; j < 4; ++j) bfr[j] = *(const bf8v*)&Bs[(wn + j * 16 + lm) * LSTR + quad * 8];
    #pragma unroll
    for (int i = 0; i < 4; ++i)
      #pragma unroll
      for (int j = 0; j < 4; ++j)
        acc[i][j] = __builtin_amdgcn_mfma_f32_16x16x32_bf16(af[i], bfr[j], acc[i][j], 0, 0, 0);
  }
  #pragma unroll
  for (int j = 0; j < 4; ++j){
    int n = n0 + wn + j * 16 + lm;
    float badd = b1 ? b1[n] : 0.f;
    #pragma unroll
    for (int i = 0; i < 4; ++i){
      int mb = m0 + wm + i * 16 + quad * 4;
      #pragma unroll
      for (int reg = 0; reg < 4; ++reg){
        int m = mb + reg;
        float v = acc[i][j][reg] + badd;
        if (C0) v += C0[(size_t)m * N + n];
        if (obf16) ((u16*)out)[(size_t)m * N + n] = f2bf(v);
        else       ((float*)out)[(size_t)m * N + n] = v;
      }
    }
  }
}

__global__ __launch_bounds__(256) void k_mgemm(
    const u16* __restrict__ A, const u16* __restrict__ W,
    const float* __restrict__ b1, const float* __restrict__ C0,
    void* __restrict__ out, int obf16, int N)
{
  __shared__ u16 As[128 * LSTR];
  __shared__ u16 Bs[128 * LSTR];
  gemm_tile(A, W, b1, C0, out, obf16, N, blockIdx.y * 128, blockIdx.x * 128, As, Bs);
}

// ---------------- fused gates GEMM + LSTM (unchanged: control) ----------------
__global__ __launch_bounds__(256, 1) void k_glstm(
    const u16* __restrict__ A1, const u16* __restrict__ W1,
    const u16* __restrict__ A2, const u16* __restrict__ W2,
    const float* __restrict__ b1, const float* __restrict__ b2,
    const float* __restrict__ Woh, const int* __restrict__ txt, int t,
    u16* __restrict__ hn, float* __restrict__ c_io,
    u16* __restrict__ hidout)
{
  __shared__ u16 As[64 * LSTR];    // 5120 B
  __shared__ u16 Bs[256 * LSTR];   // 20480 B (f32 gate-exchange in epilogue, 16 KB used)
  int tid = threadIdx.x;
  int wave = tid >> 6, lane = tid & 63;
  int lm = lane & 15, quad = lane >> 4;
  int m0 = blockIdx.y * 64, j0 = blockIdx.x * 64;
  int sr = tid >> 2;            // 0..63
  int sseg = (tid & 3) * 8;     // u16 offset
  f4v acc[4][4];
  #pragma unroll
  for (int i = 0; i < 4; ++i)
    #pragma unroll
    for (int j = 0; j < 4; ++j)
      acc[i][j] = (f4v){0.f, 0.f, 0.f, 0.f};

  const u16* a0P = A1 + (size_t)(m0 + sr) * 512 + sseg;
  const u16* b0P0 = W1 + (size_t)(0 * 512 + j0 + sr) * 512 + sseg;
  const u16* b0P1 = W1 + (size_t)(1 * 512 + j0 + sr) * 512 + sseg;
  const u16* b0P2 = W1 + (size_t)(2 * 512 + j0 + sr) * 512 + sseg;
  const u16* b0P3 = W1 + (size_t)(3 * 512 + j0 + sr) * 512 + sseg;
  const u16* a1P  = A2 ? A2 + (size_t)(m0 + sr) * 512 + sseg : a0P;
  const u16* b1P0 = A2 ? W2 + (size_t)(0 * 512 + j0 + sr) * 512 + sseg : b0P0;
  const u16* b1P1 = A2 ? W2 + (size_t)(1 * 512 + j0 + sr) * 512 + sseg : b0P1;
  const u16* b1P2 = A2 ? W2 + (size_t)(2 * 512 + j0 + sr) * 512 + sseg : b0P2;
  const u16* b1P3 = A2 ? W2 + (size_t)(3 * 512 + j0 + sr) * 512 + sseg : b0P3;
  int nit = A2 ? 32 : 16;

  us8v pav, pb0, pb1, pb2, pb3;
  auto LDG = [&](int i){
    int ps = i >> 4, kc = i & 15;
    const u16* ap  = ps ? a1P  : a0P;
    const u16* bp0 = ps ? b1P0 : b0P0;
    const u16* bp1 = ps ? b1P1 : b0P1;
    const u16* bp2 = ps ? b1P2 : b0P2;
    const u16* bp3 = ps ? b1P3 : b0P3;
    pav = *(const us8v*)(ap  + kc * 32);
    pb0 = *(const us8v*)(bp0 + kc * 32);
    pb1 = *(const us8v*)(bp1 + kc * 32);
    pb2 = *(const us8v*)(bp2 + kc * 32);
    pb3 = *(const us8v*)(bp3 + kc * 32);
  };
  LDG(0);
  for (int i = 0; i < nit; ++i){
    __syncthreads();
    *(us8v*)&As[sr * LSTR + sseg]              = pav;
    *(us8v*)&Bs[(0 * 64 + sr) * LSTR + sseg]   = pb0;
    *(us8v*)&Bs[(1 * 64 + sr) * LSTR + sseg]   = pb1;
    *(us8v*)&Bs[(2 * 64 + sr) * LSTR + sseg]   = pb2;
    *(us8v*)&Bs[(3 * 64 + sr) * LSTR + sseg]   = pb3;
    __syncthreads();
    if (i + 1 < nit) LDG(i + 1);
    bf8v af[4], bfr[4];
    #pragma unroll
    for (int mi = 0; mi < 4; ++mi) af[mi]  = *(const bf8v*)&As[(mi * 16 + lm) * LSTR + quad * 8];
    #pragma unroll
    for (int nj = 0; nj < 4; ++nj) bfr[nj] = *(const bf8v*)&Bs[(wave * 64 + nj * 16 + lm) * LSTR + quad * 8];
    #pragma unroll
    for (int mi = 0; mi < 4; ++mi)
      #pragma unroll
      for (int nj = 0; nj < 4; ++nj)
        acc[mi][nj] = __builtin_amdgcn_mfma_f32_16x16x32_bf16(af[mi], bfr[nj], acc[mi][nj], 0, 0, 0);
  }

  // epilogue: 4 chunks of 16 batch-rows; gate exchange via LDS; fully unrolled
  float* gL = (float*)Bs;   // [4 gates][16 rows][64 cols] f32 = 16 KB
  #pragma unroll
  for (int mi = 0; mi < 4; ++mi){
    __syncthreads();
    #pragma unroll
    for (int nj = 0; nj < 4; ++nj)
      #pragma unroll
      for (int reg = 0; reg < 4; ++reg)
        gL[wave * 1024 + (quad * 4 + reg) * 64 + nj * 16 + lm] = acc[mi][nj][reg];
    __syncthreads();
    #pragma unroll
    for (int p = 0; p < 4; ++p){
      int idx = p * 256 + tid;          // 16*64 = 1024 outputs
      int bl = idx >> 6, jj = idx & 63;
      int b = m0 + mi * 16 + bl;
      int j = j0 + jj;
      float gi = gL[idx];
      float gf = gL[1024 + idx];
      float gg = gL[2048 + idx];
      float go = gL[3072 + idx];
      if (b1){ gi += b1[j]; gf += b1[512 + j]; gg += b1[1024 + j]; go += b1[1536 + j]; }
      if (b2){ gi += b2[j]; gf += b2[512 + j]; gg += b2[1024 + j]; go += b2[1536 + j]; }
      if (Woh){
        int tx = txt[b * 26 + t];
        gi += Woh[(size_t)j * 550 + 512 + tx];
        gf += Woh[(size_t)(512 + j) * 550 + 512 + tx];
        gg += Woh[(size_t)(1024 + j) * 550 + 512 + tx];
        go += Woh[(size_t)(1536 + j) * 550 + 512 + tx];
      }
      float iv = sigm(gi), fv = sigm(gf), gv = tanh_(gg), ov = sigm(go);
      float c = fv * c_io[(size_t)b * 512 + j] + iv * gv;
      float h = ov * tanh_(c);
      c_io[(size_t)b * 512 + j] = c;
      u16 hb = f2bf(h);
      hn[(size_t)b * 512 + j] = hb;
      if (hidout) hidout[((size_t)(b * 26 + t)) * 512 + j] = hb;
    }
  }
}

// ---------------- small dense ops ----------------

__global__ __launch_bounds__(256) void k_meanH(const float* __restrict__ H, float* __restrict__ outm){
  int idx = blockIdx.x * 256 + threadIdx.x;  // 256*512
  int b = idx >> 9, k = idx & 511;
  float s = 0.f;
  #pragma unroll
  for (int t = 0; t < 26; ++t) s += H[((size_t)(b * 26 + t)) * 512 + k];
  outm[idx] = s * (1.f / 26.f);
}

__global__ __launch_bounds__(256) void k_pgemm(const float* __restrict__ A, const float* __restrict__ W,
                                               float* __restrict__ out){
  __shared__ float As[32][33];
  __shared__ float Ws[64][33];
  int tid = threadIdx.x;
  int n0 = blockIdx.x * 64, m0 = blockIdx.y * 32;
  float acc[2][4] = {{0.f,0.f,0.f,0.f},{0.f,0.f,0.f,0.f}};
  int ml = (tid >> 4) * 2, nl = (tid & 15) * 4;
  int sm = tid >> 3, sk = (tid & 7) * 4;
  int wn = tid >> 2, wk = (tid & 3) * 8;
  for (int k0 = 0; k0 < 512; k0 += 32){
    __syncthreads();
    float4 av = *(const float4*)&A[(size_t)(m0 + sm) * 512 + k0 + sk];
    As[sm][sk] = av.x; As[sm][sk+1] = av.y; As[sm][sk+2] = av.z; As[sm][sk+3] = av.w;
    const float* wp = W + (size_t)(n0 + wn) * 512 + k0 + wk;
    #pragma unroll
    for (int u2 = 0; u2 < 8; ++u2) Ws[wn][wk + u2] = wp[u2];
    __syncthreads();
    #pragma unroll
    for (int k = 0; k < 32; ++k){
      float a0 = As[ml][k], a1 = As[ml+1][k];
      float w0 = Ws[nl][k], w1 = Ws[nl+1][k], w2 = Ws[nl+2][k], w3 = Ws[nl+3][k];
      acc[0][0] = fmaf(a0,w0,acc[0][0]); acc[0][1] = fmaf(a0,w1,acc[0][1]);
      acc[0][2] = fmaf(a0,w2,acc[0][2]); acc[0][3] = fmaf(a0,w3,acc[0][3]);
      acc[1][0] = fmaf(a1,w0,acc[1][0]); acc[1][1] = fmaf(a1,w1,acc[1][1]);
      acc[1][2] = fmaf(a1,w2,acc[1][2]); acc[1][3] = fmaf(a1,w3,acc[1][3]);
    }
  }
  #pragma unroll
  for (int i = 0; i < 2; ++i)
    #pragma unroll
    for (int j = 0; j < 4; ++j)
      out[(size_t)(m0 + ml + i) * 512 + n0 + nl + j] = acc[i][j];
}

__global__ __launch_bounds__(256) void k_init(const float* __restrict__ hh, const float* __restrict__ hc,
                                              u16* h1, float* c1, u16* h2, float* c2){
  int idx = blockIdx.x * 256 + threadIdx.x;  // 131072
  float h0 = 0.5f * (hh[idx] + hh[idx + 131072]);
  float c0 = 0.5f * (hc[idx] + hc[idx + 131072]);
  u16 hb = f2bf(h0);
  h1[idx] = hb; h2[idx] = hb; c1[idx] = c0; c2[idx] = c0;
}

// fused q-matvec + attention, 1024 threads/block (16 waves/CU = 4/SIMD).
// Work split: q-matvec (n, m-half) / e-pass (hw, c-quarter) / ctx (c, hw-half),
// each with LDS partial-reduce. One block per batch.
__global__ __launch_bounds__(1024) void k_attnq(const u16* __restrict__ fmh,
    const u16* __restrict__ h2, const u16* __restrict__ Wqc, const float* __restrict__ q_const,
    const float* __restrict__ sw, const float* __restrict__ sb, u16* __restrict__ ctx)
{
  __shared__ float hsh[512], wss[512], qs[512], pp[1024], cp[1024], sA[256], sR[256];
  int b = blockIdx.x, tid = threadIdx.x;
  if (tid < 512) hsh[tid] = bfs(h2[b * 512 + tid]);
  else           wss[tid - 512] = sw[tid - 512];
  __syncthreads();

  // ---- q matvec: thread = (n = tid&511, m-half = tid>>9), 16 rounds of 2x16B ----
  {
    int n = tid & 511, mh = tid >> 9;
    const u16* wr = Wqc + (size_t)n * 512 + mh * 256;
    const float* hh2 = hsh + mh * 256;
    float a0 = 0.f, a1 = 0.f, a2 = 0.f, a3 = 0.f;
    for (int m = 0; m < 256; m += 16){
      us8v w0 = *(const us8v*)(wr + m);
      us8v w1 = *(const us8v*)(wr + m + 8);
      a0 = fmaf(bfs(w0[0]), hh2[m+0], a0);  a1 = fmaf(bfs(w0[1]), hh2[m+1], a1);
      a2 = fmaf(bfs(w0[2]), hh2[m+2], a2);  a3 = fmaf(bfs(w0[3]), hh2[m+3], a3);
      a0 = fmaf(bfs(w0[4]), hh2[m+4], a0);  a1 = fmaf(bfs(w0[5]), hh2[m+5], a1);
      a2 = fmaf(bfs(w0[6]), hh2[m+6], a2);  a3 = fmaf(bfs(w0[7]), hh2[m+7], a3);
      a0 = fmaf(bfs(w1[0]), hh2[m+8], a0);  a1 = fmaf(bfs(w1[1]), hh2[m+9], a1);
      a2 = fmaf(bfs(w1[2]), hh2[m+10], a2); a3 = fmaf(bfs(w1[3]), hh2[m+11], a3);
      a0 = fmaf(bfs(w1[4]), hh2[m+12], a0); a1 = fmaf(bfs(w1[5]), hh2[m+13], a1);
      a2 = fmaf(bfs(w1[6]), hh2[m+14], a2); a3 = fmaf(bfs(w1[7]), hh2[m+15], a3);
    }
    pp[tid] = (a0 + a1) + (a2 + a3);
  }
  __syncthreads();
  if (tid < 512) qs[tid] = q_const[(size_t)b * 512 + tid] + pp[tid] + pp[tid + 512];
  __syncthreads();

  // ---- e-pass: thread = (hw = tid&255, qtr = tid>>8), 128 channels each ----
  const u16* fb = fmh + (size_t)b * 512 * 256;
  {
    int hw = tid & 255, qtr = tid >> 8;
    int c0 = qtr * 128;
    float e0 = 0.f, e1 = 0.f, e2 = 0.f, e3 = 0.f;
    for (int c = c0; c < c0 + 128; c += 4){
      e0 = fmaf(tanh_(bfs(fb[(c+0)*256 + hw]) + qs[c+0]), wss[c+0], e0);
      e1 = fmaf(tanh_(bfs(fb[(c+1)*256 + hw]) + qs[c+1]), wss[c+1], e1);
      e2 = fmaf(tanh_(bfs(fb[(c+2)*256 + hw]) + qs[c+2]), wss[c+2], e2);
      e3 = fmaf(tanh_(bfs(fb[(c+3)*256 + hw]) + qs[c+3]), wss[c+3], e3);
    }
    pp[tid] = (e0 + e1) + (e2 + e3);
  }
  __syncthreads();
  float ec = 0.f;
  if (tid < 256) ec = pp[tid] + pp[tid + 256] + pp[tid + 512] + pp[tid + 768] + sb[0];
  if (tid < 256) sR[tid] = ec;
  __syncthreads();
  #pragma unroll
  for (int off = 128; off > 0; off >>= 1){
    if (tid < off) sR[tid] = fmaxf(sR[tid], sR[tid + off]);
    __syncthreads();
  }
  float mx = sR[0];
  __syncthreads();
  if (tid < 256){ float ex = __expf(ec - mx); sA[tid] = ex; sR[tid] = ex; }
  __syncthreads();
  #pragma unroll
  for (int off = 128; off > 0; off >>= 1){
    if (tid < off) sR[tid] += sR[tid + off];
    __syncthreads();
  }
  float inv = 1.f / sR[0];
  if (tid < 256) sA[tid] *= inv;
  __syncthreads();

  // ---- ctx: thread = (c = tid>>1, hw-half = tid&1), 16 rounds of 16B ----
  {
    int c = tid >> 1, half = tid & 1;
    const u16* row = fb + (size_t)c * 256 + half * 128;
    const float* al = sA + half * 128;
    float s0 = 0.f, s1 = 0.f;
    for (int h8 = 0; h8 < 16; h8 += 2){
      us8v va = *(const us8v*)(row + h8 * 8);
      us8v vb = *(const us8v*)(row + h8 * 8 + 8);
      #pragma unroll
      for (int u2 = 0; u2 < 8; ++u2){
        s0 = fmaf(al[h8*8 + u2],     bfs(va[u2]), s0);
        s1 = fmaf(al[h8*8 + 8 + u2], bfs(vb[u2]), s1);
      }
    }
    cp[tid] = s0 + s1;
  }
  __syncthreads();
  if (tid < 512) ctx[(size_t)b * 512 + tid] = f2bf(cp[2 * tid] + cp[2 * tid + 1]);
}

// final projection: out[6656][38] = hid @ genw^T + gen_b. Tile 128x48, grid 52.
__global__ __launch_bounds__(256) void k_gen(const u16* __restrict__ hid,
    const u16* __restrict__ genw, const float* __restrict__ gb, float* __restrict__ out)
{
  __shared__ u16 As[128 * LSTR];
  __shared__ u16 Bs[48 * LSTR];
  int tid = threadIdx.x;
  int wave = tid >> 6, lane = tid & 63;
  int m0 = blockIdx.x * 128;
  int r = tid >> 1, seg = (tid & 1) * 16;
  int lm = lane & 15, quad = lane >> 4;
  int mw = wave * 32;
  f4v acc[2][3];
  #pragma unroll
  for (int i = 0; i < 2; ++i)
    #pragma unroll
    for (int j = 0; j < 3; ++j)
      acc[i][j] = (f4v){0.f, 0.f, 0.f, 0.f};
  const u16* aRow = hid + (size_t)(m0 + r) * 512 + seg;
  const u16* bRow = genw + (size_t)r * 512 + seg;   // valid only tid<96
  us8v pa0 = *(const us8v*)aRow, pa1 = *(const us8v*)(aRow + 8);
  us8v pb0, pb1;
  if (tid < 96){ pb0 = *(const us8v*)bRow; pb1 = *(const us8v*)(bRow + 8); }
  for (int kc = 0; kc < 16; ++kc){
    __syncthreads();
    *(us8v*)&As[r * LSTR + seg]     = pa0;
    *(us8v*)&As[r * LSTR + seg + 8] = pa1;
    if (tid < 96){
      *(us8v*)&Bs[r * LSTR + seg]     = pb0;
      *(us8v*)&Bs[r * LSTR + seg + 8] = pb1;
    }
    __syncthreads();
    if (kc < 15){
      pa0 = *(const us8v*)(aRow + (kc + 1) * 32);
      pa1 = *(const us8v*)(aRow + (kc + 1) * 32 + 8);
      if (tid < 96){
        pb0 = *(const us8v*)(bRow + (kc + 1) * 32);
        pb1 = *(const us8v*)(bRow + (kc + 1) * 32 + 8);
      }
    }
    bf8v af[2], bfr[3];
    #pragma unroll
    for (int i = 0; i < 2; ++i) af[i]  = *(const bf8v*)&As[(mw + i * 16 + lm) * LSTR + quad * 8];
    #pragma unroll
    for (int j = 0; j < 3; ++j) bfr[j] = *(const bf8v*)&Bs[(j * 16 + lm) * LSTR + quad * 8];
    #pragma unroll
    for (int i = 0; i < 2; ++i)
      #pragma unroll
      for (int j = 0; j < 3; ++j)
        acc[i][j] = __builtin_amdgcn_mfma_f32_16x16x32_bf16(af[i], bfr[j], acc[i][j], 0, 0, 0);
  }
  #pragma unroll
  for (int j = 0; j < 3; ++j){
    int n = j * 16 + lm;
    if (n >= 38) continue;
    float bv = gb[n];
    #pragma unroll
    for (int i = 0; i < 2; ++i){
      int mb = m0 + mw + i * 16 + quad * 4;
      #pragma unroll
      for (int reg = 0; reg < 4; ++reg)
        out[(size_t)(mb + reg) * 38 + n] = acc[i][j][reg] + bv;
    }
  }
}

extern "C" void kernel_launch(void* const* d_in, const int* in_sizes, int n_in,
                              void* d_out, int out_size, void* d_ws, size_t ws_size,
                              hipStream_t stream)
{
  (void)in_sizes; (void)n_in; (void)out_size; (void)ws_size;
  const float* fm      = (const float*)d_in[0];
  const float* batchH  = (const float*)d_in[1];
  const float* hh      = (const float*)d_in[2];
  const float* hc      = (const float*)d_in[3];
  const int*   text    = (const int*)d_in[4];
  const float* i2h_w   = (const float*)d_in[5];
  const float* h2h_w   = (const float*)d_in[6];
  const float* h2h_b   = (const float*)d_in[7];
  const float* cm2h_w  = (const float*)d_in[8];
  const float* cm2h_b  = (const float*)d_in[9];
  const float* ch2h_w  = (const float*)d_in[10];
  const float* ch2h_b  = (const float*)d_in[11];
  const float* score_w = (const float*)d_in[12];
  const float* score_b = (const float*)d_in[13];
  const float* r1_wih  = (const float*)d_in[14];
  const float* r1_whh  = (const float*)d_in[15];
  const float* r1_bih  = (const float*)d_in[16];
  const float* r1_bhh  = (const float*)d_in[17];
  const float* hlin_w  = (const float*)d_in[18];
  const float* hlin_b  = (const float*)d_in[19];
  const float* r2_wih  = (const float*)d_in[20];
  const float* r2_whh  = (const float*)d_in[21];
  const float* r2_bih  = (const float*)d_in[22];
  const float* r2_bhh  = (const float*)d_in[23];
  const float* gen_w   = (const float*)d_in[24];
  const float* gen_b   = (const float*)d_in[25];

  // ---- workspace layout (within proven 88.6 MB budget) ----
  char* ws = (char*)d_ws;
  u16* fmh = (u16*)(ws + 0);                 // 67,108,864 B
  char* R  = ws + 67108864;                  // 21,495,808 B multi-phase region
  // conv phase:
  u16* Wt    = (u16*)(R + 0);                // 4,718,592
  u16* chunk = (u16*)(R + 4718592);          // 16,777,216
  // steady-state:
  u16* r1wB  = (u16*)(R + 0);                // 2,097,152
  u16* r1hB  = (u16*)(R + 2097152);          // 2,097,152
  u16* r2hB  = (u16*)(R + 4194304);          // 2,097,152
  u16* W2cB  = (u16*)(R + 6291456);          // 2,097,152
  u16* WqcB  = (u16*)(R + 8388608);          //   524,288
  float* q_const = (float*)(R + 8912896);    //   524,288
  u16* slotA = (u16*)(R + 9437184);          //   262,144  ctx ; genw overlay at epilogue
  u16* h1a   = (u16*)(R + 9961472);          //   262,144
  u16* h1b   = (u16*)(R + 10223616);         //   262,144
  u16* h2a   = (u16*)(R + 10485760);         //   262,144
  u16* h2b   = (u16*)(R + 10747904);         //   262,144
  float* c1  = (float*)(R + 11010048);       //   524,288
  float* c2  = (float*)(R + 11534336);       //   524,288
  float* b2c = (float*)(R + 12058624);       //     8,192
  float* qbias = (float*)(R + 12066816);     //     2,048
  u16* hid   = (u16*)(R + 12068864);         // 6,815,744 -> ends 18,884,608
  // precompute-only temps (overlay hid; dead before hid written):
  u16* r2wB    = (u16*)(R + 12068864);       // 2,097,152
  u16* hlinT   = (u16*)(R + 14166016);       //   524,288
  u16* h2hT    = (u16*)(R + 14690304);       //   524,288
  u16* ch2hB   = (u16*)(R + 15214592);       //   524,288
  float* bh_mean = (float*)(R + 18884608);   //   524,288 (prologue only)
  float* bh_proj = (float*)(R + 19408896);   //   524,288 (prologue only)
  u16* genw  = slotA;                        //    49,152 (epilogue overlay)

  // ---- conv phase ----
  k_wt_prep<<<9216, 256, 0, stream>>>(cm2h_w, Wt);
  for (int rb = 0; rb < 4; ++rb){
    k_transpose_fm<<<dim3(4, 8, 64), 256, 0, stream>>>(fm, chunk, rb * 64);
    k_conv<<<512, 256, 0, stream>>>(chunk, Wt, cm2h_b, fmh, rb * 64);
  }
  // ---- weight converts ----
  k_cvt_rw1<<<4096, 256, 0, stream>>>(r1_wih, r1wB);
  k_cvt<<<4096, 256, 0, stream>>>(r1_whh, r1hB, 1048576);
  k_cvt<<<4096, 256, 0, stream>>>(r2_whh, r2hB, 1048576);
  k_cvt<<<4096, 256, 0, stream>>>(r2_wih, r2wB, 1048576);
  k_cvt<<<1024, 256, 0, stream>>>(ch2h_w, ch2hB, 262144);
  k_cvt_t<<<dim3(16, 16), 256, 0, stream>>>(hlin_w, hlinT);
  k_cvt_t<<<dim3(16, 16), 256, 0, stream>>>(h2h_w, h2hT);
  // ---- folded weights ----
  k_mgemm<<<dim3(4, 16), 256, 0, stream>>>(r2wB, hlinT, nullptr, nullptr, W2cB, 1, 512);
  k_mgemm<<<dim3(4, 4), 256, 0, stream>>>(ch2hB, h2hT, nullptr, nullptr, WqcB, 1, 512);
  // ---- prologue ----
  k_meanH<<<512, 256, 0, stream>>>(batchH, bh_mean);
  k_pgemm<<<dim3(8, 8), 256, 0, stream>>>(bh_mean, i2h_w, bh_proj);
  k_bfold<<<2, 256, 0, stream>>>(ch2h_w, h2h_b, ch2h_b, nullptr, qbias, 512);
  k_pgemm<<<dim3(8, 8), 256, 0, stream>>>(bh_proj, ch2h_w, q_const);
  k_addrow<<<512, 256, 0, stream>>>(q_const, qbias);
  k_bfold<<<8, 256, 0, stream>>>(r2_wih, hlin_b, r2_bih, r2_bhh, b2c, 2048);
  k_init<<<512, 256, 0, stream>>>(hh, hc, h1a, c1, h2a, c2);

  // ---- 26-step recurrence: 3 kernels/step ----
  for (int t = 0; t < 26; ++t){
    u16* h1i = (t & 1) ? h1b : h1a;
    u16* h1o = (t & 1) ? h1a : h1b;
    u16* h2i = (t & 1) ? h2b : h2a;
    u16* h2o = (t & 1) ? h2a : h2b;
    // q (in-block matvec) + attention -> ctx in slotA (bf16)  [1024 threads]
    k_attnq<<<256, 1024, 0, stream>>>(fmh, h2i, WqcB, q_const, score_w, score_b, slotA);
    // gates1+lstm1 (2-pass): ctx@r1w^T + h1@r1h^T + biases + onehot -> h1o, c1
    k_glstm<<<dim3(8, 4), 256, 0, stream>>>(slotA, r1wB, h1i, r1hB,
        r1_bih, r1_bhh, r1_wih, text, t, h1o, c1, nullptr);
    // gates2+lstm2 (2-pass): h1o@W2c^T + h2i@r2_whh^T + b2c -> h2o, c2, hid
    k_glstm<<<dim3(8, 4), 256, 0, stream>>>(h1o, W2cB, h2i, r2hB,
        b2c, nullptr, nullptr, nullptr, t, h2o, c2, hid);
  }
  // ---- final projection ----
  k_cvt_gen<<<96, 256, 0, stream>>>(gen_w, genw);
  k_gen<<<52, 256, 0, stream>>>(hid, genw, gen_b, (float*)d_out);
}

// Round 8
// 3877.755 us; speedup vs baseline: 2.3746x; 1.0791x over previous
//
#include <hip/hip_runtime.h>
#include <stdint.h>

typedef unsigned short u16;
typedef unsigned int   u32;
typedef __attribute__((ext_vector_type(8))) short bf8v;          // 8 x bf16 MFMA frag (4 VGPR)
typedef __attribute__((ext_vector_type(4))) float f4v;           // MFMA acc frag
typedef __attribute__((ext_vector_type(8))) unsigned short us8v; // 16B bf16 vector

#define LSTR 40   // padded LDS row stride (u16) for 32-elem bf16 rows
#define AST  72   // padded LDS row stride (u16) for 64-elem bf16 rows

__device__ __forceinline__ float bfs(u16 u){ union { u32 i; float f; } v; v.i = ((u32)u) << 16; return v.f; }
__device__ __forceinline__ u16 f2bf(float f){ union { float f; u32 i; } v; v.f = f; u32 i = v.i; return (u16)((i + 0x7fffu + ((i >> 16) & 1u)) >> 16); }
__device__ __forceinline__ float sigm(float x){ return 1.f / (1.f + __expf(-x)); }
__device__ __forceinline__ float tanh_(float x){ float e = __expf(2.f * x); return 1.f - 2.f / (e + 1.f); }

// ---------------- one-time / chunked prep ----------------

__global__ __launch_bounds__(256) void k_transpose_fm(const float* __restrict__ fm, u16* __restrict__ out, int b_base){
  __shared__ u16 tile[64][65];
  int b = blockIdx.z, hw0 = blockIdx.x * 64, ci0 = blockIdx.y * 64;
  int tid = threadIdx.x;
  int hwl = tid & 63, ci_l = tid >> 6;
  #pragma unroll
  for (int r = 0; r < 16; ++r){
    int ci = ci_l * 16 + r;
    tile[ci][hwl] = f2bf(fm[((size_t)((b_base + b) * 512 + ci0 + ci)) * 256 + hw0 + hwl]);
  }
  __syncthreads();
  int cil = tid & 63, hw_l = tid >> 6;
  #pragma unroll
  for (int r = 0; r < 16; ++r){
    int hw = hw_l * 16 + r;
    out[((size_t)(b * 256 + hw0 + hw)) * 512 + ci0 + cil] = tile[cil][hw];
  }
}

__global__ __launch_bounds__(256) void k_wt_prep(const float* __restrict__ w, u16* __restrict__ wt){
  int idx = blockIdx.x * 256 + threadIdx.x;         // 9*512*512
  int ci = idx & 511, co = (idx >> 9) & 511, dydx = idx >> 18;
  wt[idx] = f2bf(w[((size_t)(co * 512 + ci)) * 9 + dydx]);
}

__global__ __launch_bounds__(256) void k_cvt(const float* __restrict__ src, u16* __restrict__ dst, int n){
  int idx = blockIdx.x * 256 + threadIdx.x;
  if (idx < n) dst[idx] = f2bf(src[idx]);
}
__global__ __launch_bounds__(256) void k_cvt_rw1(const float* __restrict__ src, u16* __restrict__ dst){
  int idx = blockIdx.x * 256 + threadIdx.x;   // 2048*512
  int n = idx >> 9, k = idx & 511;
  dst[idx] = f2bf(src[(size_t)n * 550 + k]);
}
__global__ __launch_bounds__(256) void k_cvt_gen(const float* __restrict__ src, u16* __restrict__ dst){
  int idx = blockIdx.x * 256 + threadIdx.x;   // 48*512
  int n = idx >> 9, k = idx & 511;
  dst[idx] = (n < 38) ? f2bf(src[(size_t)n * 512 + k]) : (u16)0;
}
__global__ __launch_bounds__(256) void k_cvt_t(const float* __restrict__ src, u16* __restrict__ dst){
  __shared__ float tile[32][33];
  int c0 = blockIdx.x * 32, r0 = blockIdx.y * 32;
  int tx = threadIdx.x & 31, ty = threadIdx.x >> 5;
  #pragma unroll
  for (int rr = ty; rr < 32; rr += 8)
    tile[rr][tx] = src[(size_t)(r0 + rr) * 512 + c0 + tx];
  __syncthreads();
  #pragma unroll
  for (int rr = ty; rr < 32; rr += 8)
    dst[(size_t)(c0 + rr) * 512 + r0 + tx] = f2bf(tile[tx][rr]);
}
__global__ __launch_bounds__(256) void k_bfold(const float* __restrict__ W, const float* __restrict__ vin,
    const float* __restrict__ a1, const float* __restrict__ a2, float* __restrict__ out, int N){
  int n = blockIdx.x * 256 + threadIdx.x;
  if (n >= N) return;
  float s = a1 ? a1[n] : 0.f;
  if (a2) s += a2[n];
  const float* wr = W + (size_t)n * 512;
  float acc0 = 0.f, acc1 = 0.f, acc2 = 0.f, acc3 = 0.f;
  for (int k = 0; k < 512; k += 4){
    acc0 = fmaf(wr[k],   vin[k],   acc0);
    acc1 = fmaf(wr[k+1], vin[k+1], acc1);
    acc2 = fmaf(wr[k+2], vin[k+2], acc2);
    acc3 = fmaf(wr[k+3], vin[k+3], acc3);
  }
  out[n] = s + ((acc0 + acc1) + (acc2 + acc3));
}
__global__ __launch_bounds__(256) void k_addrow(float* __restrict__ dst, const float* __restrict__ row){
  int idx = blockIdx.x * 256 + threadIdx.x;  // 131072
  dst[idx] += row[idx & 511];
}

// ---------------- conv3x3 as implicit GEMM (unchanged: control) ----------------
__global__ __launch_bounds__(256) void k_conv(
    const u16* __restrict__ in_t, const u16* __restrict__ Wt,
    const float* __restrict__ cbias, u16* __restrict__ fmh, int b_base)
{
  __shared__ u16 As[128 * LSTR];
  __shared__ u16 Bs[128 * LSTR];
  int tid = threadIdx.x;
  int wave = tid >> 6, lane = tid & 63;
  int nb = blockIdx.x & 3, mb = blockIdx.x >> 2;
  int m0 = mb * 128, n0 = nb * 128;
  int bb = m0 >> 8;
  int r = tid >> 1;
  int seg = (tid & 1) * 16;
  int hwl = (mb & 1) * 128 + r;
  int y = hwl >> 5, x = hwl & 31;
  const u16* aBase = in_t + ((size_t)bb * 256) * 512 + seg;
  const u16* bBase = Wt + ((size_t)(n0 + r)) * 512 + seg;
  int lm = lane & 15, quad = lane >> 4;
  int wm = (wave & 1) * 64, wn = (wave >> 1) * 64;
  f4v acc[4][4];
  #pragma unroll
  for (int i = 0; i < 4; ++i)
    #pragma unroll
    for (int j = 0; j < 4; ++j)
      acc[i][j] = (f4v){0.f, 0.f, 0.f, 0.f};

  us8v pa0, pa1, pb0, pb1;
  auto LDC = [&](int i){
    int dydx = i >> 4, kc = i & 15;
    int dy = dydx / 3, dx = dydx - dy * 3;
    int yy = y + dy - 1, xx = x + dx - 1;
    bool ok = (yy >= 0) && (yy < 8) && (xx >= 0) && (xx < 32);
    const u16* aRow = aBase + (ptrdiff_t)(yy * 32 + xx) * 512 + kc * 32;
    const u16* bRow = bBase + (size_t)dydx * 262144 + kc * 32;
    if (ok){ pa0 = *(const us8v*)aRow; pa1 = *(const us8v*)(aRow + 8); }
    else   { pa0 = (us8v){0,0,0,0,0,0,0,0}; pa1 = pa0; }
    pb0 = *(const us8v*)bRow; pb1 = *(const us8v*)(bRow + 8);
  };
  LDC(0);
  for (int i = 0; i < 144; ++i){
    __syncthreads();
    *(us8v*)&As[r * LSTR + seg]     = pa0;
    *(us8v*)&As[r * LSTR + seg + 8] = pa1;
    *(us8v*)&Bs[r * LSTR + seg]     = pb0;
    *(us8v*)&Bs[r * LSTR + seg + 8] = pb1;
    __syncthreads();
    if (i < 143) LDC(i + 1);
    bf8v af[4], bfr[4];
    #pragma unroll
    for (int ii = 0; ii < 4; ++ii) af[ii]  = *(const bf8v*)&As[(wm + ii * 16 + lm) * LSTR + quad * 8];
    #pragma unroll
    for (int jj = 0; jj < 4; ++jj) bfr[jj] = *(const bf8v*)&Bs[(wn + jj * 16 + lm) * LSTR + quad * 8];
    #pragma unroll
    for (int ii = 0; ii < 4; ++ii)
      #pragma unroll
      for (int jj = 0; jj < 4; ++jj)
        acc[ii][jj] = __builtin_amdgcn_mfma_f32_16x16x32_bf16(af[ii], bfr[jj], acc[ii][jj], 0, 0, 0);
  }
  #pragma unroll
  for (int j = 0; j < 4; ++j){
    int co = n0 + wn + j * 16 + lm;
    float bv = cbias[co];
    #pragma unroll
    for (int i = 0; i < 4; ++i){
      int mrow = m0 + wm + i * 16 + quad * 4;
      int hw = mrow & 255;
      ushort4 pk;
      pk.x = f2bf(acc[i][j][0] + bv);
      pk.y = f2bf(acc[i][j][1] + bv);
      pk.z = f2bf(acc[i][j][2] + bv);
      pk.w = f2bf(acc[i][j][3] + bv);
      *(ushort4*)&fmh[((size_t)((b_base + bb) * 512 + co)) * 256 + hw] = pk;
    }
  }
}

// ---------------- 128x128 GEMM tile body ----------------
__device__ __forceinline__ void gemm_tile(
    const u16* __restrict__ A, const u16* __restrict__ W,
    const float* __restrict__ b1, const float* __restrict__ C0,
    void* __restrict__ out, int obf16, int N, int m0, int n0,
    u16* As, u16* Bs)
{
  int tid = threadIdx.x;
  int wave = tid >> 6, lane = tid & 63;
  int r = tid >> 1, seg = (tid & 1) * 16;
  int lm = lane & 15, quad = lane >> 4;
  int wm = (wave & 1) * 64, wn = (wave >> 1) * 64;
  f4v acc[4][4];
  #pragma unroll
  for (int i = 0; i < 4; ++i)
    #pragma unroll
    for (int j = 0; j < 4; ++j)
      acc[i][j] = (f4v){0.f, 0.f, 0.f, 0.f};
  const u16* aRow = A + (size_t)(m0 + r) * 512 + seg;
  const u16* bRow = W + (size_t)(n0 + r) * 512 + seg;
  us8v pa0 = *(const us8v*)aRow, pa1 = *(const us8v*)(aRow + 8);
  us8v pb0 = *(const us8v*)bRow, pb1 = *(const us8v*)(bRow + 8);
  for (int kc = 0; kc < 16; ++kc){
    __syncthreads();
    *(us8v*)&As[r * LSTR + seg]     = pa0;
    *(us8v*)&As[r * LSTR + seg + 8] = pa1;
    *(us8v*)&Bs[r * LSTR + seg]     = pb0;
    *(us8v*)&Bs[r * LSTR + seg + 8] = pb1;
    __syncthreads();
    if (kc < 15){
      pa0 = *(const us8v*)(aRow + (kc + 1) * 32);
      pa1 = *(const us8v*)(aRow + (kc + 1) * 32 + 8);
      pb0 = *(const us8v*)(bRow + (kc + 1) * 32);
      pb1 = *(const us8v*)(bRow + (kc + 1) * 32 + 8);
    }
    bf8v af[4], bfr[4];
    #pragma unroll
    for (int i = 0; i < 4; ++i) af[i]  = *(const bf8v*)&As[(wm + i * 16 + lm) * LSTR + quad * 8];
    #pragma unroll
    for (int j = 0; j < 4; ++j) bfr[j] = *(const bf8v*)&Bs[(wn + j * 16 + lm) * LSTR + quad * 8];
    #pragma unroll
    for (int i = 0; i < 4; ++i)
      #pragma unroll
      for (int j = 0; j < 4; ++j)
        acc[i][j] = __builtin_amdgcn_mfma_f32_16x16x32_bf16(af[i], bfr[j], acc[i][j], 0, 0, 0);
  }
  #pragma unroll
  for (int j = 0; j < 4; ++j){
    int n = n0 + wn + j * 16 + lm;
    float badd = b1 ? b1[n] : 0.f;
    #pragma unroll
    for (int i = 0; i < 4; ++i){
      int mb = m0 + wm + i * 16 + quad * 4;
      #pragma unroll
      for (int reg = 0; reg < 4; ++reg){
        int m = mb + reg;
        float v = acc[i][j][reg] + badd;
        if (C0) v += C0[(size_t)m * N + n];
        if (obf16) ((u16*)out)[(size_t)m * N + n] = f2bf(v);
        else       ((float*)out)[(size_t)m * N + n] = v;
      }
    }
  }
}

__global__ __launch_bounds__(256) void k_mgemm(
    const u16* __restrict__ A, const u16* __restrict__ W,
    const float* __restrict__ b1, const float* __restrict__ C0,
    void* __restrict__ out, int obf16, int N)
{
  __shared__ u16 As[128 * LSTR];
  __shared__ u16 Bs[128 * LSTR];
  gemm_tile(A, W, b1, C0, out, obf16, N, blockIdx.y * 128, blockIdx.x * 128, As, Bs);
}

// ---------------- fused gates GEMM + LSTM body, BK=64 ----------------
// Tile: 64 batches (by) x 64 hidden cols (bx), 4 gates. Wave w computes gate w.
// K=512 per pass, BK=64 -> 8 iters/pass. gates = A1@W1^T (+A2@W2^T) + b1 + b2 + C0 + onehot.
__device__ __forceinline__ void glstm_body(u16* As, u16* Bs, int bx, int by,
    const u16* __restrict__ A1, const u16* __restrict__ W1,
    const u16* __restrict__ A2, const u16* __restrict__ W2,
    const float* __restrict__ b1, const float* __restrict__ b2,
    const float* __restrict__ C0,
    const float* __restrict__ Woh, const int* __restrict__ txt, int t,
    u16* __restrict__ hn, float* __restrict__ c_io,
    u16* __restrict__ hidout)
{
  int tid = threadIdx.x;
  int wave = tid >> 6, lane = tid & 63;
  int lm = lane & 15, quad = lane >> 4;
  int m0 = by * 64, j0 = bx * 64;
  int sr = tid >> 2;           // 0..63: staged row
  int sc = (tid & 3) * 16;     // elem offset within 64-elem row (chunks sc, sc+8)
  f4v acc[4][4];
  #pragma unroll
  for (int i = 0; i < 4; ++i)
    #pragma unroll
    for (int j = 0; j < 4; ++j)
      acc[i][j] = (f4v){0.f, 0.f, 0.f, 0.f};

  const u16* a0P  = A1 + (size_t)(m0 + sr) * 512 + sc;
  const u16* b0P0 = W1 + (size_t)(0 * 512 + j0 + sr) * 512 + sc;
  const u16* b0P1 = W1 + (size_t)(1 * 512 + j0 + sr) * 512 + sc;
  const u16* b0P2 = W1 + (size_t)(2 * 512 + j0 + sr) * 512 + sc;
  const u16* b0P3 = W1 + (size_t)(3 * 512 + j0 + sr) * 512 + sc;
  const u16* a1P  = A2 ? A2 + (size_t)(m0 + sr) * 512 + sc : a0P;
  const u16* b1P0 = A2 ? W2 + (size_t)(0 * 512 + j0 + sr) * 512 + sc : b0P0;
  const u16* b1P1 = A2 ? W2 + (size_t)(1 * 512 + j0 + sr) * 512 + sc : b0P1;
  const u16* b1P2 = A2 ? W2 + (size_t)(2 * 512 + j0 + sr) * 512 + sc : b0P2;
  const u16* b1P3 = A2 ? W2 + (size_t)(3 * 512 + j0 + sr) * 512 + sc : b0P3;
  int nit = A2 ? 16 : 8;

  us8v pa0, pa1, pb00, pb01, pb10, pb11, pb20, pb21, pb30, pb31;
  auto LDG = [&](int i){
    int ps = i >> 3, kc = (i & 7) * 64;
    const u16* ap  = ps ? a1P  : a0P;
    const u16* bp0 = ps ? b1P0 : b0P0;
    const u16* bp1 = ps ? b1P1 : b0P1;
    const u16* bp2 = ps ? b1P2 : b0P2;
    const u16* bp3 = ps ? b1P3 : b0P3;
    pa0  = *(const us8v*)(ap  + kc);  pa1  = *(const us8v*)(ap  + kc + 8);
    pb00 = *(const us8v*)(bp0 + kc);  pb01 = *(const us8v*)(bp0 + kc + 8);
    pb10 = *(const us8v*)(bp1 + kc);  pb11 = *(const us8v*)(bp1 + kc + 8);
    pb20 = *(const us8v*)(bp2 + kc);  pb21 = *(const us8v*)(bp2 + kc + 8);
    pb30 = *(const us8v*)(bp3 + kc);  pb31 = *(const us8v*)(bp3 + kc + 8);
  };
  LDG(0);
  for (int i = 0; i < nit; ++i){
    __syncthreads();
    *(us8v*)&As[sr * AST + sc]                  = pa0;
    *(us8v*)&As[sr * AST + sc + 8]              = pa1;
    *(us8v*)&Bs[(0 * 64 + sr) * AST + sc]       = pb00;
    *(us8v*)&Bs[(0 * 64 + sr) * AST + sc + 8]   = pb01;
    *(us8v*)&Bs[(1 * 64 + sr) * AST + sc]       = pb10;
    *(us8v*)&Bs[(1 * 64 + sr) * AST + sc + 8]   = pb11;
    *(us8v*)&Bs[(2 * 64 + sr) * AST + sc]       = pb20;
    *(us8v*)&Bs[(2 * 64 + sr) * AST + sc + 8]   = pb21;
    *(us8v*)&Bs[(3 * 64 + sr) * AST + sc]       = pb30;
    *(us8v*)&Bs[(3 * 64 + sr) * AST + sc + 8]   = pb31;
    __syncthreads();
    if (i + 1 < nit) LDG(i + 1);
    bf8v af[2][4], bfr[2][4];
    #pragma unroll
    for (int kk = 0; kk < 2; ++kk){
      #pragma unroll
      for (int mi = 0; mi < 4; ++mi)
        af[kk][mi]  = *(const bf8v*)&As[(mi * 16 + lm) * AST + kk * 32 + quad * 8];
      #pragma unroll
      for (int nj = 0; nj < 4; ++nj)
        bfr[kk][nj] = *(const bf8v*)&Bs[(wave * 64 + nj * 16 + lm) * AST + kk * 32 + quad * 8];
    }
    #pragma unroll
    for (int kk = 0; kk < 2; ++kk)
      #pragma unroll
      for (int mi = 0; mi < 4; ++mi)
        #pragma unroll
        for (int nj = 0; nj < 4; ++nj)
          acc[mi][nj] = __builtin_amdgcn_mfma_f32_16x16x32_bf16(af[kk][mi], bfr[kk][nj], acc[mi][nj], 0, 0, 0);
  }

  // epilogue: 4 chunks of 16 batch-rows; gate exchange via LDS; fully unrolled
  float* gL = (float*)Bs;   // [4 gates][16 rows][64 cols] f32 = 16 KB (fits in Bs)
  #pragma unroll
  for (int mi = 0; mi < 4; ++mi){
    __syncthreads();
    #pragma unroll
    for (int nj = 0; nj < 4; ++nj)
      #pragma unroll
      for (int reg = 0; reg < 4; ++reg)
        gL[wave * 1024 + (quad * 4 + reg) * 64 + nj * 16 + lm] = acc[mi][nj][reg];
    __syncthreads();
    #pragma unroll
    for (int p = 0; p < 4; ++p){
      int idx = p * 256 + tid;          // 16*64 = 1024 outputs
      int bl = idx >> 6, jj = idx & 63;
      int b = m0 + mi * 16 + bl;
      int j = j0 + jj;
      float gi = gL[idx];
      float gf = gL[1024 + idx];
      float gg = gL[2048 + idx];
      float go = gL[3072 + idx];
      if (b1){ gi += b1[j]; gf += b1[512 + j]; gg += b1[1024 + j]; go += b1[1536 + j]; }
      if (b2){ gi += b2[j]; gf += b2[512 + j]; gg += b2[1024 + j]; go += b2[1536 + j]; }
      if (C0){
        const float* cb = C0 + (size_t)b * 2048 + j;
        gi += cb[0]; gf += cb[512]; gg += cb[1024]; go += cb[1536];
      }
      if (Woh){
        int tx = txt[b * 26 + t];
        gi += Woh[(size_t)j * 550 + 512 + tx];
        gf += Woh[(size_t)(512 + j) * 550 + 512 + tx];
        gg += Woh[(size_t)(1024 + j) * 550 + 512 + tx];
        go += Woh[(size_t)(1536 + j) * 550 + 512 + tx];
      }
      float iv = sigm(gi), fv = sigm(gf), gv = tanh_(gg), ov = sigm(go);
      float c = fv * c_io[(size_t)b * 512 + j] + iv * gv;
      float h = ov * tanh_(c);
      c_io[(size_t)b * 512 + j] = c;
      u16 hb = f2bf(h);
      hn[(size_t)b * 512 + j] = hb;
      if (hidout) hidout[((size_t)(b * 26 + t)) * 512 + j] = hb;
    }
  }
}

// glstm1 launch: blocks 0..31 = gates1+lstm1 (2-pass); blocks 32..63 = gbuf GEMM
// (gbuf = h2@r2_whh^T + b2c via 128x128 gemm_tile) on otherwise-idle CUs.
__global__ __launch_bounds__(256, 1) void k_glstm1(
    const u16* __restrict__ ctx, const u16* __restrict__ r1w,
    const u16* __restrict__ h1i, const u16* __restrict__ r1h,
    const float* __restrict__ b1, const float* __restrict__ b2,
    const float* __restrict__ Woh, const int* __restrict__ txt, int t,
    u16* __restrict__ h1o, float* __restrict__ c1,
    const u16* __restrict__ h2i, const u16* __restrict__ r2h,
    const float* __restrict__ b2c, float* __restrict__ gbuf)
{
  __shared__ u16 lds[(64 + 256) * AST];   // 46080 B; gemm_tile needs 10240 u16 (fits)
  int bx = blockIdx.x;
  if (bx < 32){
    glstm_body(lds, lds + 64 * AST, bx & 7, bx >> 3, ctx, r1w, h1i, r1h,
               b1, b2, nullptr, Woh, txt, t, h1o, c1, nullptr);
  } else {
    int i = bx - 32;   // 32 tiles: M=256 (2), N=2048 (16)
    gemm_tile(h2i, r2h, b2c, nullptr, gbuf, 0, 2048,
              (i >> 4) * 128, (i & 15) * 128, lds, lds + 128 * LSTR);
  }
}

// glstm2: 1-pass (h1o@W2c^T) + C0=gbuf -> h2o, c2, hid
__global__ __launch_bounds__(256, 1) void k_glstm2(
    const u16* __restrict__ h1o, const u16* __restrict__ W2c,
    const float* __restrict__ C0, int t,
    u16* __restrict__ h2o, float* __restrict__ c2, u16* __restrict__ hid)
{
  __shared__ u16 As[64 * AST];
  __shared__ u16 Bs[256 * AST];
  glstm_body(As, Bs, blockIdx.x & 7, blockIdx.x >> 3, h1o, W2c, nullptr, nullptr,
             nullptr, nullptr, C0, nullptr, nullptr, t, h2o, c2, hid);
}

// ---------------- small dense ops ----------------

__global__ __launch_bounds__(256) void k_meanH(const float* __restrict__ H, float* __restrict__ outm){
  int idx = blockIdx.x * 256 + threadIdx.x;  // 256*512
  int b = idx >> 9, k = idx & 511;
  float s = 0.f;
  #pragma unroll
  for (int t = 0; t < 26; ++t) s += H[((size_t)(b * 26 + t)) * 512 + k];
  outm[idx] = s * (1.f / 26.f);
}

__global__ __launch_bounds__(256) void k_pgemm(const float* __restrict__ A, const float* __restrict__ W,
                                               float* __restrict__ out){
  __shared__ float As[32][33];
  __shared__ float Ws[64][33];
  int tid = threadIdx.x;
  int n0 = blockIdx.x * 64, m0 = blockIdx.y * 32;
  float acc[2][4] = {{0.f,0.f,0.f,0.f},{0.f,0.f,0.f,0.f}};
  int ml = (tid >> 4) * 2, nl = (tid & 15) * 4;
  int sm = tid >> 3, sk = (tid & 7) * 4;
  int wn = tid >> 2, wk = (tid & 3) * 8;
  for (int k0 = 0; k0 < 512; k0 += 32){
    __syncthreads();
    float4 av = *(const float4*)&A[(size_t)(m0 + sm) * 512 + k0 + sk];
    As[sm][sk] = av.x; As[sm][sk+1] = av.y; As[sm][sk+2] = av.z; As[sm][sk+3] = av.w;
    const float* wp = W + (size_t)(n0 + wn) * 512 + k0 + wk;
    #pragma unroll
    for (int u2 = 0; u2 < 8; ++u2) Ws[wn][wk + u2] = wp[u2];
    __syncthreads();
    #pragma unroll
    for (int k = 0; k < 32; ++k){
      float a0 = As[ml][k], a1 = As[ml+1][k];
      float w0 = Ws[nl][k], w1 = Ws[nl+1][k], w2 = Ws[nl+2][k], w3 = Ws[nl+3][k];
      acc[0][0] = fmaf(a0,w0,acc[0][0]); acc[0][1] = fmaf(a0,w1,acc[0][1]);
      acc[0][2] = fmaf(a0,w2,acc[0][2]); acc[0][3] = fmaf(a0,w3,acc[0][3]);
      acc[1][0] = fmaf(a1,w0,acc[1][0]); acc[1][1] = fmaf(a1,w1,acc[1][1]);
      acc[1][2] = fmaf(a1,w2,acc[1][2]); acc[1][3] = fmaf(a1,w3,acc[1][3]);
    }
  }
  #pragma unroll
  for (int i = 0; i < 2; ++i)
    #pragma unroll
    for (int j = 0; j < 4; ++j)
      out[(size_t)(m0 + ml + i) * 512 + n0 + nl + j] = acc[i][j];
}

__global__ __launch_bounds__(256) void k_init(const float* __restrict__ hh, const float* __restrict__ hc,
                                              u16* h1, float* c1, u16* h2, float* c2){
  int idx = blockIdx.x * 256 + threadIdx.x;  // 131072
  float h0 = 0.5f * (hh[idx] + hh[idx + 131072]);
  float c0 = 0.5f * (hc[idx] + hc[idx + 131072]);
  u16 hb = f2bf(h0);
  h1[idx] = hb; h2[idx] = hb; c1[idx] = c0; c2[idx] = c0;
}

// fused q-matvec + attention, 1024 threads/block (unchanged: control)
__global__ __launch_bounds__(1024) void k_attnq(const u16* __restrict__ fmh,
    const u16* __restrict__ h2, const u16* __restrict__ Wqc, const float* __restrict__ q_const,
    const float* __restrict__ sw, const float* __restrict__ sb, u16* __restrict__ ctx)
{
  __shared__ float hsh[512], wss[512], qs[512], pp[1024], cp[1024], sA[256], sR[256];
  int b = blockIdx.x, tid = threadIdx.x;
  if (tid < 512) hsh[tid] = bfs(h2[b * 512 + tid]);
  else           wss[tid - 512] = sw[tid - 512];
  __syncthreads();

  {
    int n = tid & 511, mh = tid >> 9;
    const u16* wr = Wqc + (size_t)n * 512 + mh * 256;
    const float* hh2 = hsh + mh * 256;
    float a0 = 0.f, a1 = 0.f, a2 = 0.f, a3 = 0.f;
    for (int m = 0; m < 256; m += 16){
      us8v w0 = *(const us8v*)(wr + m);
      us8v w1 = *(const us8v*)(wr + m + 8);
      a0 = fmaf(bfs(w0[0]), hh2[m+0], a0);  a1 = fmaf(bfs(w0[1]), hh2[m+1], a1);
      a2 = fmaf(bfs(w0[2]), hh2[m+2], a2);  a3 = fmaf(bfs(w0[3]), hh2[m+3], a3);
      a0 = fmaf(bfs(w0[4]), hh2[m+4], a0);  a1 = fmaf(bfs(w0[5]), hh2[m+5], a1);
      a2 = fmaf(bfs(w0[6]), hh2[m+6], a2);  a3 = fmaf(bfs(w0[7]), hh2[m+7], a3);
      a0 = fmaf(bfs(w1[0]), hh2[m+8], a0);  a1 = fmaf(bfs(w1[1]), hh2[m+9], a1);
      a2 = fmaf(bfs(w1[2]), hh2[m+10], a2); a3 = fmaf(bfs(w1[3]), hh2[m+11], a3);
      a0 = fmaf(bfs(w1[4]), hh2[m+12], a0); a1 = fmaf(bfs(w1[5]), hh2[m+13], a1);
      a2 = fmaf(bfs(w1[6]), hh2[m+14], a2); a3 = fmaf(bfs(w1[7]), hh2[m+15], a3);
    }
    pp[tid] = (a0 + a1) + (a2 + a3);
  }
  __syncthreads();
  if (tid < 512) qs[tid] = q_const[(size_t)b * 512 + tid] + pp[tid] + pp[tid + 512];
  __syncthreads();

  const u16* fb = fmh + (size_t)b * 512 * 256;
  {
    int hw = tid & 255, qtr = tid >> 8;
    int c0 = qtr * 128;
    float e0 = 0.f, e1 = 0.f, e2 = 0.f, e3 = 0.f;
    for (int c = c0; c < c0 + 128; c += 4){
      e0 = fmaf(tanh_(bfs(fb[(c+0)*256 + hw]) + qs[c+0]), wss[c+0], e0);
      e1 = fmaf(tanh_(bfs(fb[(c+1)*256 + hw]) + qs[c+1]), wss[c+1], e1);
      e2 = fmaf(tanh_(bfs(fb[(c+2)*256 + hw]) + qs[c+2]), wss[c+2], e2);
      e3 = fmaf(tanh_(bfs(fb[(c+3)*256 + hw]) + qs[c+3]), wss[c+3], e3);
    }
    pp[tid] = (e0 + e1) + (e2 + e3);
  }
  __syncthreads();
  float ec = 0.f;
  if (tid < 256) ec = pp[tid] + pp[tid + 256] + pp[tid + 512] + pp[tid + 768] + sb[0];
  if (tid < 256) sR[tid] = ec;
  __syncthreads();
  #pragma unroll
  for (int off = 128; off > 0; off >>= 1){
    if (tid < off) sR[tid] = fmaxf(sR[tid], sR[tid + off]);
    __syncthreads();
  }
  float mx = sR[0];
  __syncthreads();
  if (tid < 256){ float ex = __expf(ec - mx); sA[tid] = ex; sR[tid] = ex; }
  __syncthreads();
  #pragma unroll
  for (int off = 128; off > 0; off >>= 1){
    if (tid < off) sR[tid] += sR[tid + off];
    __syncthreads();
  }
  float inv = 1.f / sR[0];
  if (tid < 256) sA[tid] *= inv;
  __syncthreads();

  {
    int c = tid >> 1, half = tid & 1;
    const u16* row = fb + (size_t)c * 256 + half * 128;
    const float* al = sA + half * 128;
    float s0 = 0.f, s1 = 0.f;
    for (int h8 = 0; h8 < 16; h8 += 2){
      us8v va = *(const us8v*)(row + h8 * 8);
      us8v vb = *(const us8v*)(row + h8 * 8 + 8);
      #pragma unroll
      for (int u2 = 0; u2 < 8; ++u2){
        s0 = fmaf(al[h8*8 + u2],     bfs(va[u2]), s0);
        s1 = fmaf(al[h8*8 + 8 + u2], bfs(vb[u2]), s1);
      }
    }
    cp[tid] = s0 + s1;
  }
  __syncthreads();
  if (tid < 512) ctx[(size_t)b * 512 + tid] = f2bf(cp[2 * tid] + cp[2 * tid + 1]);
}

// final projection: out[6656][38] = hid @ genw^T + gen_b. Tile 128x48, grid 52.
__global__ __launch_bounds__(256) void k_gen(const u16* __restrict__ hid,
    const u16* __restrict__ genw, const float* __restrict__ gb, float* __restrict__ out)
{
  __shared__ u16 As[128 * LSTR];
  __shared__ u16 Bs[48 * LSTR];
  int tid = threadIdx.x;
  int wave = tid >> 6, lane = tid & 63;
  int m0 = blockIdx.x * 128;
  int r = tid >> 1, seg = (tid & 1) * 16;
  int lm = lane & 15, quad = lane >> 4;
  int mw = wave * 32;
  f4v acc[2][3];
  #pragma unroll
  for (int i = 0; i < 2; ++i)
    #pragma unroll
    for (int j = 0; j < 3; ++j)
      acc[i][j] = (f4v){0.f, 0.f, 0.f, 0.f};
  const u16* aRow = hid + (size_t)(m0 + r) * 512 + seg;
  const u16* bRow = genw + (size_t)r * 512 + seg;   // valid only tid<96
  us8v pa0 = *(const us8v*)aRow, pa1 = *(const us8v*)(aRow + 8);
  us8v pb0, pb1;
  if (tid < 96){ pb0 = *(const us8v*)bRow; pb1 = *(const us8v*)(bRow + 8); }
  for (int kc = 0; kc < 16; ++kc){
    __syncthreads();
    *(us8v*)&As[r * LSTR + seg]     = pa0;
    *(us8v*)&As[r * LSTR + seg + 8] = pa1;
    if (tid < 96){
      *(us8v*)&Bs[r * LSTR + seg]     = pb0;
      *(us8v*)&Bs[r * LSTR + seg + 8] = pb1;
    }
    __syncthreads();
    if (kc < 15){
      pa0 = *(const us8v*)(aRow + (kc + 1) * 32);
      pa1 = *(const us8v*)(aRow + (kc + 1) * 32 + 8);
      if (tid < 96){
        pb0 = *(const us8v*)(bRow + (kc + 1) * 32);
        pb1 = *(const us8v*)(bRow + (kc + 1) * 32 + 8);
      }
    }
    bf8v af[2], bfr[3];
    #pragma unroll
    for (int i = 0; i < 2; ++i) af[i]  = *(const bf8v*)&As[(mw + i * 16 + lm) * LSTR + quad * 8];
    #pragma unroll
    for (int j = 0; j < 3; ++j) bfr[j] = *(const bf8v*)&Bs[(j * 16 + lm) * LSTR + quad * 8];
    #pragma unroll
    for (int i = 0; i < 2; ++i)
      #pragma unroll
      for (int j = 0; j < 3; ++j)
        acc[i][j] = __builtin_amdgcn_mfma_f32_16x16x32_bf16(af[i], bfr[j], acc[i][j], 0, 0, 0);
  }
  #pragma unroll
  for (int j = 0; j < 3; ++j){
    int n = j * 16 + lm;
    if (n >= 38) continue;
    float bv = gb[n];
    #pragma unroll
    for (int i = 0; i < 2; ++i){
      int mb = m0 + mw + i * 16 + quad * 4;
      #pragma unroll
      for (int reg = 0; reg < 4; ++reg)
        out[(size_t)(mb + reg) * 38 + n] = acc[i][j][reg] + bv;
    }
  }
}

extern "C" void kernel_launch(void* const* d_in, const int* in_sizes, int n_in,
                              void* d_out, int out_size, void* d_ws, size_t ws_size,
                              hipStream_t stream)
{
  (void)in_sizes; (void)n_in; (void)out_size; (void)ws_size;
  const float* fm      = (const float*)d_in[0];
  const float* batchH  = (const float*)d_in[1];
  const float* hh      = (const float*)d_in[2];
  const float* hc      = (const float*)d_in[3];
  const int*   text    = (const int*)d_in[4];
  const float* i2h_w   = (const float*)d_in[5];
  const float* h2h_w   = (const float*)d_in[6];
  const float* h2h_b   = (const float*)d_in[7];
  const float* cm2h_w  = (const float*)d_in[8];
  const float* cm2h_b  = (const float*)d_in[9];
  const float* ch2h_w  = (const float*)d_in[10];
  const float* ch2h_b  = (const float*)d_in[11];
  const float* score_w = (const float*)d_in[12];
  const float* score_b = (const float*)d_in[13];
  const float* r1_wih  = (const float*)d_in[14];
  const float* r1_whh  = (const float*)d_in[15];
  const float* r1_bih  = (const float*)d_in[16];
  const float* r1_bhh  = (const float*)d_in[17];
  const float* hlin_w  = (const float*)d_in[18];
  const float* hlin_b  = (const float*)d_in[19];
  const float* r2_wih  = (const float*)d_in[20];
  const float* r2_whh  = (const float*)d_in[21];
  const float* r2_bih  = (const float*)d_in[22];
  const float* r2_bhh  = (const float*)d_in[23];
  const float* gen_w   = (const float*)d_in[24];
  const float* gen_b   = (const float*)d_in[25];

  // ---- workspace layout (within proven 88.6 MB budget) ----
  char* ws = (char*)d_ws;
  u16* fmh = (u16*)(ws + 0);                 // 67,108,864 B
  char* R  = ws + 67108864;                  // 21,495,808 B multi-phase region
  // conv phase:
  u16* Wt    = (u16*)(R + 0);                // 4,718,592
  u16* chunk = (u16*)(R + 4718592);          // 16,777,216
  // steady-state:
  u16* r1wB  = (u16*)(R + 0);                // 2,097,152
  u16* r1hB  = (u16*)(R + 2097152);          // 2,097,152
  u16* r2hB  = (u16*)(R + 4194304);          // 2,097,152
  u16* W2cB  = (u16*)(R + 6291456);          // 2,097,152
  u16* WqcB  = (u16*)(R + 8388608);          //   524,288
  float* q_const = (float*)(R + 8912896);    //   524,288
  u16* slotA = (u16*)(R + 9437184);          //   262,144  ctx ; genw overlay at epilogue
  u16* h1a   = (u16*)(R + 9961472);          //   262,144
  u16* h1b   = (u16*)(R + 10223616);         //   262,144
  u16* h2a   = (u16*)(R + 10485760);         //   262,144
  u16* h2b   = (u16*)(R + 10747904);         //   262,144
  float* c1  = (float*)(R + 11010048);       //   524,288
  float* c2  = (float*)(R + 11534336);       //   524,288
  float* b2c = (float*)(R + 12058624);       //     8,192
  float* qbias = (float*)(R + 12066816);     //     2,048
  u16* hid   = (u16*)(R + 12068864);         // 6,815,744 -> ends 18,884,608
  // precompute-only temps (overlay hid; dead before hid written):
  u16* r2wB    = (u16*)(R + 12068864);       // 2,097,152
  u16* hlinT   = (u16*)(R + 14166016);       //   524,288
  u16* h2hT    = (u16*)(R + 14690304);       //   524,288
  u16* ch2hB   = (u16*)(R + 15214592);       //   524,288
  float* bh_mean = (float*)(R + 18884608);   //   524,288 (prologue only)
  float* bh_proj = (float*)(R + 19408896);   //   524,288 (prologue only)
  // recurrence-phase overlay (dead after prologue):
  float* gbuf = (float*)(R + 18884608);      // 2,097,152 gates2 h2-partial -> ends 20,981,760
  u16* genw  = slotA;                        //    49,152 (epilogue overlay)

  // ---- conv phase ----
  k_wt_prep<<<9216, 256, 0, stream>>>(cm2h_w, Wt);
  for (int rb = 0; rb < 4; ++rb){
    k_transpose_fm<<<dim3(4, 8, 64), 256, 0, stream>>>(fm, chunk, rb * 64);
    k_conv<<<512, 256, 0, stream>>>(chunk, Wt, cm2h_b, fmh, rb * 64);
  }
  // ---- weight converts ----
  k_cvt_rw1<<<4096, 256, 0, stream>>>(r1_wih, r1wB);
  k_cvt<<<4096, 256, 0, stream>>>(r1_whh, r1hB, 1048576);
  k_cvt<<<4096, 256, 0, stream>>>(r2_whh, r2hB, 1048576);
  k_cvt<<<4096, 256, 0, stream>>>(r2_wih, r2wB, 1048576);
  k_cvt<<<1024, 256, 0, stream>>>(ch2h_w, ch2hB, 262144);
  k_cvt_t<<<dim3(16, 16), 256, 0, stream>>>(hlin_w, hlinT);
  k_cvt_t<<<dim3(16, 16), 256, 0, stream>>>(h2h_w, h2hT);
  // ---- folded weights ----
  k_mgemm<<<dim3(4, 16), 256, 0, stream>>>(r2wB, hlinT, nullptr, nullptr, W2cB, 1, 512);
  k_mgemm<<<dim3(4, 4), 256, 0, stream>>>(ch2hB, h2hT, nullptr, nullptr, WqcB, 1, 512);
  // ---- prologue ----
  k_meanH<<<512, 256, 0, stream>>>(batchH, bh_mean);
  k_pgemm<<<dim3(8, 8), 256, 0, stream>>>(bh_mean, i2h_w, bh_proj);
  k_bfold<<<2, 256, 0, stream>>>(ch2h_w, h2h_b, ch2h_b, nullptr, qbias, 512);
  k_pgemm<<<dim3(8, 8), 256, 0, stream>>>(bh_proj, ch2h_w, q_const);
  k_addrow<<<512, 256, 0, stream>>>(q_const, qbias);
  k_bfold<<<8, 256, 0, stream>>>(r2_wih, hlin_b, r2_bih, r2_bhh, b2c, 2048);
  k_init<<<512, 256, 0, stream>>>(hh, hc, h1a, c1, h2a, c2);

  // ---- 26-step recurrence: 3 kernels/step ----
  for (int t = 0; t < 26; ++t){
    u16* h1i = (t & 1) ? h1b : h1a;
    u16* h1o = (t & 1) ? h1a : h1b;
    u16* h2i = (t & 1) ? h2b : h2a;
    u16* h2o = (t & 1) ? h2a : h2b;
    // q (in-block matvec) + attention -> ctx in slotA (bf16)  [1024 threads]
    k_attnq<<<256, 1024, 0, stream>>>(fmh, h2i, WqcB, q_const, score_w, score_b, slotA);
    // gates1+lstm1 (BK=64, 16 iters) || gbuf = h2@r2_whh^T + b2c (blocks 32..63)
    k_glstm1<<<64, 256, 0, stream>>>(slotA, r1wB, h1i, r1hB,
        r1_bih, r1_bhh, r1_wih, text, t, h1o, c1, h2i, r2hB, b2c, gbuf);
    // gates2+lstm2 (BK=64, 8 iters, 1-pass + gbuf) -> h2o, c2, hid
    k_glstm2<<<32, 256, 0, stream>>>(h1o, W2cB, gbuf, t, h2o, c2, hid);
  }
  // ---- final projection ----
  k_cvt_gen<<<96, 256, 0, stream>>>(gen_w, genw);
  k_gen<<<52, 256, 0, stream>>>(hid, genw, gen_b, (float*)d_out);
}